// Round 2
// baseline (2501.267 us; speedup 1.0000x reference)
//
#include <hip/hip_runtime.h>
#include <math.h>

#define BNUM 32
#define TT   512
#define DD   768
#define HH   12
#define DHH  64
#define RR   8
#define TSRC 256     // src (even) / dst (odd) token count
#define UNM  248     // unmerged src tokens
#define TM   504     // tokens after merge
#define MROW 16128   // BNUM * TM

// ---------------------------------------------------------------------------
// Kernel 1: reduce Wk over heads -> Wkr (768x64), bkr (64)
__global__ __launch_bounds__(256) void wkr_kernel(
    const float* __restrict__ Wk, const float* __restrict__ bk,
    float* __restrict__ Wkr, float* __restrict__ bkr) {
  int idx = blockIdx.x * 256 + threadIdx.x;   // 0..49151
  int d = idx >> 6, j = idx & 63;
  float s = 0.f;
  #pragma unroll
  for (int h = 0; h < HH; ++h) s += Wk[(size_t)d * DD + h * DHH + j];
  Wkr[idx] = s * (1.f / 12.f);
  if (idx < 64) {
    float sb = 0.f;
    #pragma unroll
    for (int h = 0; h < HH; ++h) sb += bk[h * DHH + idx];
    bkr[idx] = sb * (1.f / 12.f);
  }
}

// ---------------------------------------------------------------------------
// Generic fp32 GEMM: C(MxN) = A(MxK) @ W(KxN) + bias (+ Res)
// BM=BN=64, BK=32, 256 threads, 4x4 microtile. M%64==0, N%64==0, K%32==0.
template <bool ADD_RES>
__global__ __launch_bounds__(256) void gemm_kernel(
    const float* __restrict__ A, const float* __restrict__ W,
    const float* __restrict__ bias, const float* __restrict__ Res,
    float* __restrict__ C, int M, int N, int K) {
  __shared__ float As[32][68];   // [kk][m] transposed
  __shared__ float Ws[32][68];   // [kk][n]
  const int t  = threadIdx.x;
  const int m0 = blockIdx.x * 64;
  const int n0 = blockIdx.y * 64;
  const int tx = t & 15, ty = t >> 4;

  const int a_kk = t & 31;
  const int a_m0 = t >> 5;     // rows a_m0 + 8*l
  const int w_n  = t & 63;
  const int w_k0 = t >> 6;     // rows w_k0*8 + l

  float4 acc[4];
  #pragma unroll
  for (int i = 0; i < 4; ++i) acc[i] = make_float4(0.f, 0.f, 0.f, 0.f);

  for (int k0 = 0; k0 < K; k0 += 32) {
    #pragma unroll
    for (int l = 0; l < 8; ++l) {
      int m = a_m0 + 8 * l;
      As[a_kk][m] = A[(size_t)(m0 + m) * K + k0 + a_kk];
    }
    #pragma unroll
    for (int l = 0; l < 8; ++l) {
      int kk = w_k0 * 8 + l;
      Ws[kk][w_n] = W[(size_t)(k0 + kk) * N + n0 + w_n];
    }
    __syncthreads();
    #pragma unroll
    for (int kk = 0; kk < 32; ++kk) {
      float4 a4 = *(const float4*)&As[kk][ty * 4];
      float4 w4 = *(const float4*)&Ws[kk][tx * 4];
      acc[0].x += a4.x * w4.x; acc[0].y += a4.x * w4.y; acc[0].z += a4.x * w4.z; acc[0].w += a4.x * w4.w;
      acc[1].x += a4.y * w4.x; acc[1].y += a4.y * w4.y; acc[1].z += a4.y * w4.z; acc[1].w += a4.y * w4.w;
      acc[2].x += a4.z * w4.x; acc[2].y += a4.z * w4.y; acc[2].z += a4.z * w4.z; acc[2].w += a4.z * w4.w;
      acc[3].x += a4.w * w4.x; acc[3].y += a4.w * w4.y; acc[3].z += a4.w * w4.z; acc[3].w += a4.w * w4.w;
    }
    __syncthreads();
  }

  const float4 b4 = *(const float4*)&bias[n0 + tx * 4];
  #pragma unroll
  for (int i = 0; i < 4; ++i) {
    size_t row = (size_t)(m0 + ty * 4 + i);
    size_t off = row * N + n0 + tx * 4;
    float4 v = acc[i];
    v.x += b4.x; v.y += b4.y; v.z += b4.z; v.w += b4.w;
    if (ADD_RES) {
      float4 r = *(const float4*)&Res[off];
      v.x += r.x; v.y += r.y; v.z += r.z; v.w += r.w;
    }
    *(float4*)&C[off] = v;
  }
}

// ---------------------------------------------------------------------------
// Kernel 3: per-batch bipartite soft matching indices.
// One block (256 threads) per batch. Thread i handles src token 2i.
__global__ __launch_bounds__(256) void tome_kernel(
    const float* __restrict__ metric, int* __restrict__ order_g,
    int* __restrict__ dst_g) {
  __shared__ float sm[TSRC * 64];              // 64 KB: b-rows, later keys
  int b = blockIdx.x, i = threadIdx.x;
  const float* Mb = metric + (size_t)b * TT * 64;

  // normalized a-row (even token) into registers
  float areg[64];
  float na = 0.f;
  #pragma unroll
  for (int d = 0; d < 64; ++d) {
    float v = Mb[(size_t)(2 * i) * 64 + d];
    areg[d] = v; na += v * v;
  }
  float ia = 1.f / (sqrtf(na) + 1e-6f);
  #pragma unroll
  for (int d = 0; d < 64; ++d) areg[d] *= ia;

  // normalized b-row (odd token) into LDS
  float nb = 0.f;
  #pragma unroll
  for (int d = 0; d < 64; ++d) {
    float v = Mb[(size_t)(2 * i + 1) * 64 + d];
    sm[i * 64 + d] = v; nb += v * v;
  }
  float ib = 1.f / (sqrtf(nb) + 1e-6f);
  #pragma unroll
  for (int d = 0; d < 64; ++d) sm[i * 64 + d] *= ib;
  __syncthreads();

  // row-max over all dst candidates (argmax keeps first occurrence)
  float best = -INFINITY; int besti = 0;
  for (int c = 0; c < TSRC; ++c) {
    float s = 0.f;
    #pragma unroll
    for (int d = 0; d < 64; ++d) s += areg[d] * sm[c * 64 + d];
    if (s > best) { best = s; besti = c; }
  }
  if (i == 0) best = -INFINITY;   // protect token 0
  __syncthreads();                // done reading b-rows

  // reuse LDS: keys, node_idx, order
  sm[i] = best;
  int* smi = (int*)(sm + TSRC);   // node_idx
  smi[i] = besti;
  __syncthreads();

  // stable descending rank (matches jnp.argsort(-node_max))
  float ki = sm[i];
  int r = 0;
  for (int j = 0; j < TSRC; ++j) {
    float kj = sm[j];
    if (kj > ki || (kj == ki && j < i)) ++r;
  }
  int* ord = smi + TSRC;
  ord[r] = i;
  __syncthreads();

  order_g[b * TSRC + i] = ord[i];
  if (i < RR) dst_g[b * RR + i] = smi[ord[i]];
}

// ---------------------------------------------------------------------------
// Kernel 4: merge X (B,512,768) -> Xm (B,504,768). One block per output row.
__global__ __launch_bounds__(256) void merge_kernel(
    const float* __restrict__ X, const int* __restrict__ order,
    const int* __restrict__ dsti, float* __restrict__ Xm) {
  int row = blockIdx.x;                 // 0..MROW-1
  int b = row / TM, t2 = row % TM;
  int c = threadIdx.x;
  const float* Xb = X + (size_t)b * TT * DD;
  float out[3];
  if (t2 < UNM) {
    int tok = 2 * order[b * TSRC + RR + t2];
    #pragma unroll
    for (int l = 0; l < 3; ++l) out[l] = Xb[(size_t)tok * DD + c + 256 * l];
  } else {
    int j = t2 - UNM;
    float cnt = 1.f;
    #pragma unroll
    for (int l = 0; l < 3; ++l) out[l] = Xb[(size_t)(2 * j + 1) * DD + c + 256 * l];
    for (int m = 0; m < RR; ++m) {
      if (dsti[b * RR + m] == j) {
        int tok = 2 * order[b * TSRC + m];
        #pragma unroll
        for (int l = 0; l < 3; ++l) out[l] += Xb[(size_t)tok * DD + c + 256 * l];
        cnt += 1.f;
      }
    }
    float inv = 1.f / cnt;
    #pragma unroll
    for (int l = 0; l < 3; ++l) out[l] *= inv;
  }
  #pragma unroll
  for (int l = 0; l < 3; ++l) Xm[(size_t)row * DD + c + 256 * l] = out[l];
}

// ---------------------------------------------------------------------------
// Kernel 5: flash-style attention, fp32. Block = one (b,h,q-tile of 64).
// 256 threads: thread t -> q-row (t>>2), 16-col group (t&3).
// NOTE: ctx may alias Q — Q is fully register-staged before any ctx write,
// and each block writes exactly the (rows, head-cols) region it staged.
#define NQT 8
__global__ __launch_bounds__(256) void attn_kernel(
    const float* __restrict__ Q, const float* __restrict__ K,
    const float* __restrict__ V, float* __restrict__ ctx) {
  __shared__ float Ks[64][68];
  __shared__ float Vs[64][68];
  __shared__ float QP[64][68];   // Q staging, then P tile (transposed [kk][qi])

  int blk = blockIdx.x;
  int qt = blk % NQT;
  int bh = blk / NQT;
  int h = bh % HH, b = bh / HH;
  const int t = threadIdx.x;
  int q0 = qt * 64;
  const size_t base = (size_t)b * TM * DD + (size_t)h * DHH;

  // stage Q tile -> registers
  int dcol = t & 63, rgrp = t >> 6;
  #pragma unroll
  for (int l = 0; l < 16; ++l) {
    int qi = rgrp * 16 + l;
    int row = q0 + qi;
    QP[qi][dcol] = (row < TM) ? Q[base + (size_t)row * DD + dcol] : 0.f;
  }
  __syncthreads();
  const int qi = t >> 2;      // 0..63
  const int cg = t & 3;       // 0..3
  float4 qreg[16];
  #pragma unroll
  for (int d4 = 0; d4 < 16; ++d4) qreg[d4] = *(const float4*)&QP[qi][d4 * 4];
  __syncthreads();            // everyone done reading Q before P overwrites

  float m_i = -INFINITY, l_i = 0.f;
  float4 o[4];
  #pragma unroll
  for (int j = 0; j < 4; ++j) o[j] = make_float4(0.f, 0.f, 0.f, 0.f);

  for (int kt = 0; kt < NQT; ++kt) {
    int k0 = kt * 64;
    int kn = TM - k0; if (kn > 64) kn = 64;
    __syncthreads();          // previous iteration fully consumed K/V/P
    #pragma unroll
    for (int l = 0; l < 16; ++l) {
      int kk = rgrp * 16 + l;
      int row = k0 + kk;
      float kv = 0.f, vv = 0.f;
      if (row < TM) {
        kv = K[base + (size_t)row * DD + dcol];
        vv = V[base + (size_t)row * DD + dcol];
      }
      Ks[kk][dcol] = kv;
      Vs[kk][dcol] = vv;
    }
    __syncthreads();

    // S tile: 16 scores per thread
    float s[16];
    #pragma unroll
    for (int u = 0; u < 16; ++u) s[u] = 0.f;
    #pragma unroll
    for (int d4 = 0; d4 < 16; ++d4) {
      float4 q4 = qreg[d4];
      #pragma unroll
      for (int u = 0; u < 16; ++u) {
        float4 k4 = *(const float4*)&Ks[cg * 16 + u][d4 * 4];
        s[u] += q4.x * k4.x + q4.y * k4.y + q4.z * k4.z + q4.w * k4.w;
      }
    }
    float tmax = -INFINITY;
    #pragma unroll
    for (int u = 0; u < 16; ++u) {
      int kk = cg * 16 + u;
      s[u] = (kk < kn) ? s[u] * 0.125f : -INFINITY;
      tmax = fmaxf(tmax, s[u]);
    }
    tmax = fmaxf(tmax, __shfl_xor(tmax, 1));
    tmax = fmaxf(tmax, __shfl_xor(tmax, 2));
    float new_m = fmaxf(m_i, tmax);
    float alpha = (m_i == -INFINITY) ? 0.f : __expf(m_i - new_m);
    float psum = 0.f;
    #pragma unroll
    for (int u = 0; u < 16; ++u) {
      float p = __expf(s[u] - new_m);
      QP[cg * 16 + u][qi] = p;     // P transposed
      psum += p;
    }
    psum += __shfl_xor(psum, 1);
    psum += __shfl_xor(psum, 2);
    l_i = l_i * alpha + psum;
    m_i = new_m;
    #pragma unroll
    for (int j = 0; j < 4; ++j) {
      o[j].x *= alpha; o[j].y *= alpha; o[j].z *= alpha; o[j].w *= alpha;
    }
    __syncthreads();              // P tile complete

    // PV: thread accumulates dims cg*16 .. cg*16+15
    for (int kk = 0; kk < 64; ++kk) {
      float p = QP[kk][qi];
      #pragma unroll
      for (int j = 0; j < 4; ++j) {
        float4 v4 = *(const float4*)&Vs[kk][cg * 16 + 4 * j];
        o[j].x += p * v4.x; o[j].y += p * v4.y; o[j].z += p * v4.z; o[j].w += p * v4.w;
      }
    }
  }

  float inv_l = 1.f / l_i;
  int row = q0 + qi;
  if (row < TM) {
    size_t g = base + (size_t)row * DD + cg * 16;
    #pragma unroll
    for (int j = 0; j < 4; ++j) {
      float4 ov = o[j];
      ov.x *= inv_l; ov.y *= inv_l; ov.z *= inv_l; ov.w *= inv_l;
      *(float4*)&ctx[g + 4 * j] = ov;
    }
  }
}

// ---------------------------------------------------------------------------
// Kernel 7: in-place LayerNorm on d_out rows (768 wide). One block per row.
__global__ __launch_bounds__(256) void ln_kernel(
    float* __restrict__ Y, const float* __restrict__ g,
    const float* __restrict__ beta) {
  __shared__ float red[4];
  int row = blockIdx.x, t = threadIdx.x;
  size_t baseo = (size_t)row * DD;
  float x[3];
  #pragma unroll
  for (int l = 0; l < 3; ++l) x[l] = Y[baseo + t + 256 * l];
  float s = x[0] + x[1] + x[2];
  #pragma unroll
  for (int off = 32; off > 0; off >>= 1) s += __shfl_down(s, off, 64);
  if ((t & 63) == 0) red[t >> 6] = s;
  __syncthreads();
  float mu = (red[0] + red[1] + red[2] + red[3]) * (1.f / 768.f);
  __syncthreads();
  float d0 = x[0] - mu, d1 = x[1] - mu, d2 = x[2] - mu;
  float sq = d0 * d0 + d1 * d1 + d2 * d2;
  #pragma unroll
  for (int off = 32; off > 0; off >>= 1) sq += __shfl_down(sq, off, 64);
  if ((t & 63) == 0) red[t >> 6] = sq;
  __syncthreads();
  float var = (red[0] + red[1] + red[2] + red[3]) * (1.f / 768.f);
  float inv = rsqrtf(var + 1e-12f);
  #pragma unroll
  for (int l = 0; l < 3; ++l) {
    int c = t + 256 * l;
    Y[baseo + c] = (x[l] - mu) * inv * g[c] + beta[c];
  }
}

// ---------------------------------------------------------------------------
extern "C" void kernel_launch(void* const* d_in, const int* in_sizes, int n_in,
                              void* d_out, int out_size, void* d_ws, size_t ws_size,
                              hipStream_t stream) {
  const float* X    = (const float*)d_in[0];
  const float* Wq   = (const float*)d_in[1];
  const float* bq   = (const float*)d_in[2];
  const float* Wk   = (const float*)d_in[3];
  const float* bk   = (const float*)d_in[4];
  const float* Wv   = (const float*)d_in[5];
  const float* bv   = (const float*)d_in[6];
  const float* Wo   = (const float*)d_in[7];
  const float* bo   = (const float*)d_in[8];
  const float* ln_g = (const float*)d_in[9];
  const float* ln_b = (const float*)d_in[10];
  float* out = (float*)d_out;

  // workspace layout (fp32 elements)
  const size_t metric_n = (size_t)16384 * 64;     // 4 MB
  const size_t wkr_n    = (size_t)768 * 64 + 64;
  const size_t idx_n    = (size_t)BNUM * TSRC + BNUM * RR;  // ints, same 4B
  const size_t buf_n    = (size_t)MROW * DD;      // 49.5 MB each
  const size_t needed   = (metric_n + wkr_n + idx_n + 4 * buf_n) * 4;
  if (ws_size < needed) return;   // refuse to scribble past workspace

  float* ws = (float*)d_ws;
  float* metric  = ws;
  float* Wkr     = metric + metric_n;
  float* bkr     = Wkr + (size_t)768 * 64;
  int*   order_g = (int*)(bkr + 64);
  int*   dst_g   = order_g + BNUM * TSRC;
  float* Xm      = (float*)(dst_g + BNUM * RR);
  float* Qm      = Xm  + buf_n;
  float* Km      = Qm  + buf_n;
  float* Vm      = Km  + buf_n;
  float* ctx     = Qm;            // alias: safe, see attn_kernel note

  // 1. reduce Wk over heads
  wkr_kernel<<<(768 * 64) / 256, 256, 0, stream>>>(Wk, bk, Wkr, bkr);
  // 2. metric = X @ Wkr + bkr   (16384 x 768 x 64)
  gemm_kernel<false><<<dim3(16384 / 64, 1), 256, 0, stream>>>(
      X, Wkr, bkr, nullptr, metric, 16384, 64, 768);
  // 3. bipartite indices
  tome_kernel<<<BNUM, 256, 0, stream>>>(metric, order_g, dst_g);
  // 4. merge tokens (residual)
  merge_kernel<<<MROW, 256, 0, stream>>>(X, order_g, dst_g, Xm);
  // 5. Q/K/V projections on merged tokens
  gemm_kernel<false><<<dim3(MROW / 64, DD / 64), 256, 0, stream>>>(
      Xm, Wq, bq, nullptr, Qm, MROW, DD, DD);
  gemm_kernel<false><<<dim3(MROW / 64, DD / 64), 256, 0, stream>>>(
      Xm, Wk, bk, nullptr, Km, MROW, DD, DD);
  gemm_kernel<false><<<dim3(MROW / 64, DD / 64), 256, 0, stream>>>(
      Xm, Wv, bv, nullptr, Vm, MROW, DD, DD);
  // 6. attention (ctx aliases Qm)
  attn_kernel<<<BNUM * HH * NQT, 256, 0, stream>>>(Qm, Km, Vm, ctx);
  // 7. output projection + bias + residual -> d_out
  gemm_kernel<true><<<dim3(MROW / 64, DD / 64), 256, 0, stream>>>(
      ctx, Wo, bo, Xm, out, MROW, DD, DD);
  // 8. in-place layernorm
  ln_kernel<<<MROW, 256, 0, stream>>>(out, ln_g, ln_b);
}

// Round 3
// 2156.571 us; speedup vs baseline: 1.1598x; 1.1598x over previous
//
#include <hip/hip_runtime.h>
#include <math.h>

#define BNUM 32
#define TT   512
#define DD   768
#define HH   12
#define DHH  64
#define RR   8
#define TSRC 256     // src (even) / dst (odd) token count
#define UNM  248     // unmerged src tokens
#define TM   504     // tokens after merge
#define MROW 16128   // BNUM * TM

// ---------------------------------------------------------------------------
// Kernel 1: reduce Wk over heads -> Wkr (768x64), bkr (64)
__global__ __launch_bounds__(256) void wkr_kernel(
    const float* __restrict__ Wk, const float* __restrict__ bk,
    float* __restrict__ Wkr, float* __restrict__ bkr) {
  int idx = blockIdx.x * 256 + threadIdx.x;   // 0..49151
  int d = idx >> 6, j = idx & 63;
  float s = 0.f;
  #pragma unroll
  for (int h = 0; h < HH; ++h) s += Wk[(size_t)d * DD + h * DHH + j];
  Wkr[idx] = s * (1.f / 12.f);
  if (idx < 64) {
    float sb = 0.f;
    #pragma unroll
    for (int h = 0; h < HH; ++h) sb += bk[h * DHH + idx];
    bkr[idx] = sb * (1.f / 12.f);
  }
}

// ---------------------------------------------------------------------------
// Generic fp32 GEMM: C(MxN) = A(MxK) @ W(KxN) + bias (+ Res)
// BM=BN=64, BK=32, 256 threads, 4x4 microtile. M%64==0, N%64==0, K%32==0.
template <bool ADD_RES>
__global__ __launch_bounds__(256) void gemm_kernel(
    const float* __restrict__ A, const float* __restrict__ W,
    const float* __restrict__ bias, const float* __restrict__ Res,
    float* __restrict__ C, int M, int N, int K) {
  __shared__ float As[32][68];   // [kk][m] transposed
  __shared__ float Ws[32][68];   // [kk][n]
  const int t  = threadIdx.x;
  const int m0 = blockIdx.x * 64;
  const int n0 = blockIdx.y * 64;
  const int tx = t & 15, ty = t >> 4;

  const int a_kk = t & 31;
  const int a_m0 = t >> 5;     // rows a_m0 + 8*l
  const int w_n  = t & 63;
  const int w_k0 = t >> 6;     // rows w_k0*8 + l

  float4 acc[4];
  #pragma unroll
  for (int i = 0; i < 4; ++i) acc[i] = make_float4(0.f, 0.f, 0.f, 0.f);

  for (int k0 = 0; k0 < K; k0 += 32) {
    #pragma unroll
    for (int l = 0; l < 8; ++l) {
      int m = a_m0 + 8 * l;
      As[a_kk][m] = A[(size_t)(m0 + m) * K + k0 + a_kk];
    }
    #pragma unroll
    for (int l = 0; l < 8; ++l) {
      int kk = w_k0 * 8 + l;
      Ws[kk][w_n] = W[(size_t)(k0 + kk) * N + n0 + w_n];
    }
    __syncthreads();
    #pragma unroll
    for (int kk = 0; kk < 32; ++kk) {
      float4 a4 = *(const float4*)&As[kk][ty * 4];
      float4 w4 = *(const float4*)&Ws[kk][tx * 4];
      acc[0].x += a4.x * w4.x; acc[0].y += a4.x * w4.y; acc[0].z += a4.x * w4.z; acc[0].w += a4.x * w4.w;
      acc[1].x += a4.y * w4.x; acc[1].y += a4.y * w4.y; acc[1].z += a4.y * w4.z; acc[1].w += a4.y * w4.w;
      acc[2].x += a4.z * w4.x; acc[2].y += a4.z * w4.y; acc[2].z += a4.z * w4.z; acc[2].w += a4.z * w4.w;
      acc[3].x += a4.w * w4.x; acc[3].y += a4.w * w4.y; acc[3].z += a4.w * w4.z; acc[3].w += a4.w * w4.w;
    }
    __syncthreads();
  }

  const float4 b4 = *(const float4*)&bias[n0 + tx * 4];
  #pragma unroll
  for (int i = 0; i < 4; ++i) {
    size_t row = (size_t)(m0 + ty * 4 + i);
    size_t off = row * N + n0 + tx * 4;
    float4 v = acc[i];
    v.x += b4.x; v.y += b4.y; v.z += b4.z; v.w += b4.w;
    if (ADD_RES) {
      float4 r = *(const float4*)&Res[off];
      v.x += r.x; v.y += r.y; v.z += r.z; v.w += r.w;
    }
    *(float4*)&C[off] = v;
  }
}

// ---------------------------------------------------------------------------
// Kernel 3: per-batch bipartite soft matching indices.
// One block (256 threads) per batch. Thread i handles src token 2i.
__global__ __launch_bounds__(256) void tome_kernel(
    const float* __restrict__ metric, int* __restrict__ order_g,
    int* __restrict__ dst_g) {
  __shared__ float sm[TSRC * 64];              // 64 KB: b-rows, later keys
  int b = blockIdx.x, i = threadIdx.x;
  const float* Mb = metric + (size_t)b * TT * 64;

  // normalized a-row (even token) into registers
  float areg[64];
  float na = 0.f;
  #pragma unroll
  for (int d = 0; d < 64; ++d) {
    float v = Mb[(size_t)(2 * i) * 64 + d];
    areg[d] = v; na += v * v;
  }
  float ia = 1.f / (sqrtf(na) + 1e-6f);
  #pragma unroll
  for (int d = 0; d < 64; ++d) areg[d] *= ia;

  // normalized b-row (odd token) into LDS
  float nb = 0.f;
  #pragma unroll
  for (int d = 0; d < 64; ++d) {
    float v = Mb[(size_t)(2 * i + 1) * 64 + d];
    sm[i * 64 + d] = v; nb += v * v;
  }
  float ib = 1.f / (sqrtf(nb) + 1e-6f);
  #pragma unroll
  for (int d = 0; d < 64; ++d) sm[i * 64 + d] *= ib;
  __syncthreads();

  // row-max over all dst candidates (argmax keeps first occurrence)
  float best = -INFINITY; int besti = 0;
  for (int c = 0; c < TSRC; ++c) {
    float s = 0.f;
    #pragma unroll
    for (int d = 0; d < 64; ++d) s += areg[d] * sm[c * 64 + d];
    if (s > best) { best = s; besti = c; }
  }
  if (i == 0) best = -INFINITY;   // protect token 0
  __syncthreads();                // done reading b-rows

  // reuse LDS: keys, node_idx, order
  sm[i] = best;
  int* smi = (int*)(sm + TSRC);   // node_idx
  smi[i] = besti;
  __syncthreads();

  // stable descending rank (matches jnp.argsort(-node_max))
  float ki = sm[i];
  int r = 0;
  for (int j = 0; j < TSRC; ++j) {
    float kj = sm[j];
    if (kj > ki || (kj == ki && j < i)) ++r;
  }
  int* ord = smi + TSRC;
  ord[r] = i;
  __syncthreads();

  order_g[b * TSRC + i] = ord[i];
  if (i < RR) dst_g[b * RR + i] = smi[ord[i]];
}

// ---------------------------------------------------------------------------
// Kernel 4: merge X (B,512,768) -> Xm (B,504,768). One block per output row.
__global__ __launch_bounds__(256) void merge_kernel(
    const float* __restrict__ X, const int* __restrict__ order,
    const int* __restrict__ dsti, float* __restrict__ Xm) {
  int row = blockIdx.x;                 // 0..MROW-1
  int b = row / TM, t2 = row % TM;
  int c = threadIdx.x;
  const float* Xb = X + (size_t)b * TT * DD;
  float out[3];
  if (t2 < UNM) {
    int tok = 2 * order[b * TSRC + RR + t2];
    #pragma unroll
    for (int l = 0; l < 3; ++l) out[l] = Xb[(size_t)tok * DD + c + 256 * l];
  } else {
    int j = t2 - UNM;
    float cnt = 1.f;
    #pragma unroll
    for (int l = 0; l < 3; ++l) out[l] = Xb[(size_t)(2 * j + 1) * DD + c + 256 * l];
    for (int m = 0; m < RR; ++m) {
      if (dsti[b * RR + m] == j) {
        int tok = 2 * order[b * TSRC + m];
        #pragma unroll
        for (int l = 0; l < 3; ++l) out[l] += Xb[(size_t)tok * DD + c + 256 * l];
        cnt += 1.f;
      }
    }
    float inv = 1.f / cnt;
    #pragma unroll
    for (int l = 0; l < 3; ++l) out[l] *= inv;
  }
  #pragma unroll
  for (int l = 0; l < 3; ++l) Xm[(size_t)row * DD + c + 256 * l] = out[l];
}

// ---------------------------------------------------------------------------
// Kernel 5: flash-style attention, fp32. Block = one (b,h,q-tile of 64).
// 256 threads: thread t -> q-row (t>>2), k-interleave group cg=(t&3).
// Thread (qi,cg) computes scores for k-rows 4u+cg (u=0..15) -> the 4 rows
// read simultaneously by a wave are consecutive -> distinct LDS bank groups
// (stride 68: bank = 4*row mod 32), eliminating the 4-way conflicts of the
// previous cg*16+u mapping. P stored untransposed QP[qi][kk] (2-way only).
// NOTE: ctx may alias Q — Q is fully register-staged before any ctx write.
#define NQT 8
__global__ __launch_bounds__(256) void attn_kernel(
    const float* __restrict__ Q, const float* __restrict__ K,
    const float* __restrict__ V, float* __restrict__ ctx) {
  __shared__ float Ks[64][68];
  __shared__ float Vs[64][68];
  __shared__ float QP[64][68];   // Q staging, then P tile [qi][kk]

  int blk = blockIdx.x;
  int qt = blk % NQT;
  int bh = blk / NQT;
  int h = bh % HH, b = bh / HH;
  const int t = threadIdx.x;
  int q0 = qt * 64;
  const size_t base = (size_t)b * TM * DD + (size_t)h * DHH;

  // stage Q tile -> registers
  int dcol = t & 63, rgrp = t >> 6;
  #pragma unroll
  for (int l = 0; l < 16; ++l) {
    int qi = rgrp * 16 + l;
    int row = q0 + qi;
    QP[qi][dcol] = (row < TM) ? Q[base + (size_t)row * DD + dcol] : 0.f;
  }
  __syncthreads();
  const int qi = t >> 2;      // 0..63
  const int cg = t & 3;       // 0..3
  float4 qreg[16];
  #pragma unroll
  for (int d4 = 0; d4 < 16; ++d4) qreg[d4] = *(const float4*)&QP[qi][d4 * 4];
  __syncthreads();            // everyone done reading Q before P overwrites

  float m_i = -INFINITY, l_i = 0.f;
  float4 o[4];
  #pragma unroll
  for (int j = 0; j < 4; ++j) o[j] = make_float4(0.f, 0.f, 0.f, 0.f);

  for (int kt = 0; kt < NQT; ++kt) {
    int k0 = kt * 64;
    int kn = TM - k0; if (kn > 64) kn = 64;
    __syncthreads();          // previous iteration fully consumed K/V/P
    #pragma unroll
    for (int l = 0; l < 16; ++l) {
      int kk = rgrp * 16 + l;
      int row = k0 + kk;
      float kv = 0.f, vv = 0.f;
      if (row < TM) {
        kv = K[base + (size_t)row * DD + dcol];
        vv = V[base + (size_t)row * DD + dcol];
      }
      Ks[kk][dcol] = kv;
      Vs[kk][dcol] = vv;
    }
    __syncthreads();

    // S tile: 16 scores per thread, thread's k-row for s[u] is 4u+cg
    float s[16];
    #pragma unroll
    for (int u = 0; u < 16; ++u) s[u] = 0.f;
    #pragma unroll
    for (int d4 = 0; d4 < 16; ++d4) {
      float4 q4 = qreg[d4];
      #pragma unroll
      for (int u = 0; u < 16; ++u) {
        float4 k4 = *(const float4*)&Ks[4 * u + cg][d4 * 4];
        s[u] += q4.x * k4.x + q4.y * k4.y + q4.z * k4.z + q4.w * k4.w;
      }
    }
    float tmax = -INFINITY;
    #pragma unroll
    for (int u = 0; u < 16; ++u) {
      int kk = 4 * u + cg;
      s[u] = (kk < kn) ? s[u] * 0.125f : -INFINITY;
      tmax = fmaxf(tmax, s[u]);
    }
    tmax = fmaxf(tmax, __shfl_xor(tmax, 1));
    tmax = fmaxf(tmax, __shfl_xor(tmax, 2));
    float new_m = fmaxf(m_i, tmax);
    float alpha = (m_i == -INFINITY) ? 0.f : __expf(m_i - new_m);
    float psum = 0.f;
    #pragma unroll
    for (int u = 0; u < 16; ++u) {
      float p = __expf(s[u] - new_m);
      QP[qi][4 * u + cg] = p;      // P untransposed
      psum += p;
    }
    psum += __shfl_xor(psum, 1);
    psum += __shfl_xor(psum, 2);
    l_i = l_i * alpha + psum;
    m_i = new_m;
    #pragma unroll
    for (int j = 0; j < 4; ++j) {
      o[j].x *= alpha; o[j].y *= alpha; o[j].z *= alpha; o[j].w *= alpha;
    }
    __syncthreads();              // P tile complete

    // PV: thread accumulates dims cg*16 .. cg*16+15; read P as float4
    #pragma unroll
    for (int kk4 = 0; kk4 < 16; ++kk4) {
      float4 p4 = *(const float4*)&QP[qi][kk4 * 4];
      const float* pv = &p4.x;
      #pragma unroll
      for (int c = 0; c < 4; ++c) {
        float p = pv[c];
        #pragma unroll
        for (int j = 0; j < 4; ++j) {
          float4 v4 = *(const float4*)&Vs[kk4 * 4 + c][cg * 16 + 4 * j];
          o[j].x += p * v4.x; o[j].y += p * v4.y; o[j].z += p * v4.z; o[j].w += p * v4.w;
        }
      }
    }
  }

  float inv_l = 1.f / l_i;
  int row = q0 + qi;
  if (row < TM) {
    size_t g = base + (size_t)row * DD + cg * 16;
    #pragma unroll
    for (int j = 0; j < 4; ++j) {
      float4 ov = o[j];
      ov.x *= inv_l; ov.y *= inv_l; ov.z *= inv_l; ov.w *= inv_l;
      *(float4*)&ctx[g + 4 * j] = ov;
    }
  }
}

// ---------------------------------------------------------------------------
// Kernel 7: in-place LayerNorm on d_out rows (768 wide). One block per row.
__global__ __launch_bounds__(256) void ln_kernel(
    float* __restrict__ Y, const float* __restrict__ g,
    const float* __restrict__ beta) {
  __shared__ float red[4];
  int row = blockIdx.x, t = threadIdx.x;
  size_t baseo = (size_t)row * DD;
  float x[3];
  #pragma unroll
  for (int l = 0; l < 3; ++l) x[l] = Y[baseo + t + 256 * l];
  float s = x[0] + x[1] + x[2];
  #pragma unroll
  for (int off = 32; off > 0; off >>= 1) s += __shfl_down(s, off, 64);
  if ((t & 63) == 0) red[t >> 6] = s;
  __syncthreads();
  float mu = (red[0] + red[1] + red[2] + red[3]) * (1.f / 768.f);
  __syncthreads();
  float d0 = x[0] - mu, d1 = x[1] - mu, d2 = x[2] - mu;
  float sq = d0 * d0 + d1 * d1 + d2 * d2;
  #pragma unroll
  for (int off = 32; off > 0; off >>= 1) sq += __shfl_down(sq, off, 64);
  if ((t & 63) == 0) red[t >> 6] = sq;
  __syncthreads();
  float var = (red[0] + red[1] + red[2] + red[3]) * (1.f / 768.f);
  float inv = rsqrtf(var + 1e-12f);
  #pragma unroll
  for (int l = 0; l < 3; ++l) {
    int c = t + 256 * l;
    Y[baseo + c] = (x[l] - mu) * inv * g[c] + beta[c];
  }
}

// ---------------------------------------------------------------------------
extern "C" void kernel_launch(void* const* d_in, const int* in_sizes, int n_in,
                              void* d_out, int out_size, void* d_ws, size_t ws_size,
                              hipStream_t stream) {
  const float* X    = (const float*)d_in[0];
  const float* Wq   = (const float*)d_in[1];
  const float* bq   = (const float*)d_in[2];
  const float* Wk   = (const float*)d_in[3];
  const float* bk   = (const float*)d_in[4];
  const float* Wv   = (const float*)d_in[5];
  const float* bv   = (const float*)d_in[6];
  const float* Wo   = (const float*)d_in[7];
  const float* bo   = (const float*)d_in[8];
  const float* ln_g = (const float*)d_in[9];
  const float* ln_b = (const float*)d_in[10];
  float* out = (float*)d_out;

  // workspace layout (fp32 elements)
  const size_t metric_n = (size_t)16384 * 64;     // 4 MB
  const size_t wkr_n    = (size_t)768 * 64 + 64;
  const size_t idx_n    = (size_t)BNUM * TSRC + BNUM * RR;  // ints, same 4B
  const size_t buf_n    = (size_t)MROW * DD;      // 49.5 MB each
  const size_t needed   = (metric_n + wkr_n + idx_n + 4 * buf_n) * 4;
  if (ws_size < needed) return;   // refuse to scribble past workspace

  float* ws = (float*)d_ws;
  float* metric  = ws;
  float* Wkr     = metric + metric_n;
  float* bkr     = Wkr + (size_t)768 * 64;
  int*   order_g = (int*)(bkr + 64);
  int*   dst_g   = order_g + BNUM * TSRC;
  float* Xm      = (float*)(dst_g + BNUM * RR);
  float* Qm      = Xm  + buf_n;
  float* Km      = Qm  + buf_n;
  float* Vm      = Km  + buf_n;
  float* ctx     = Qm;            // alias: safe, see attn_kernel note

  // 1. reduce Wk over heads
  wkr_kernel<<<(768 * 64) / 256, 256, 0, stream>>>(Wk, bk, Wkr, bkr);
  // 2. metric = X @ Wkr + bkr   (16384 x 768 x 64)
  gemm_kernel<false><<<dim3(16384 / 64, 1), 256, 0, stream>>>(
      X, Wkr, bkr, nullptr, metric, 16384, 64, 768);
  // 3. bipartite indices
  tome_kernel<<<BNUM, 256, 0, stream>>>(metric, order_g, dst_g);
  // 4. merge tokens (residual)
  merge_kernel<<<MROW, 256, 0, stream>>>(X, order_g, dst_g, Xm);
  // 5. Q/K/V projections on merged tokens
  gemm_kernel<false><<<dim3(MROW / 64, DD / 64), 256, 0, stream>>>(
      Xm, Wq, bq, nullptr, Qm, MROW, DD, DD);
  gemm_kernel<false><<<dim3(MROW / 64, DD / 64), 256, 0, stream>>>(
      Xm, Wk, bk, nullptr, Km, MROW, DD, DD);
  gemm_kernel<false><<<dim3(MROW / 64, DD / 64), 256, 0, stream>>>(
      Xm, Wv, bv, nullptr, Vm, MROW, DD, DD);
  // 6. attention (ctx aliases Qm)
  attn_kernel<<<BNUM * HH * NQT, 256, 0, stream>>>(Qm, Km, Vm, ctx);
  // 7. output projection + bias + residual -> d_out
  gemm_kernel<true><<<dim3(MROW / 64, DD / 64), 256, 0, stream>>>(
      ctx, Wo, bo, Xm, out, MROW, DD, DD);
  // 8. in-place layernorm
  ln_kernel<<<MROW, 256, 0, stream>>>(out, ln_g, ln_b);
}

// Round 4
// 1945.677 us; speedup vs baseline: 1.2856x; 1.1084x over previous
//
#include <hip/hip_runtime.h>
#include <math.h>

#define BNUM 32
#define TT   512
#define DD   768
#define HH   12
#define DHH  64
#define RR   8
#define TSRC 256     // src (even) / dst (odd) token count
#define UNM  248     // unmerged src tokens
#define TM   504     // tokens after merge
#define MROW 16128   // BNUM * TM

typedef unsigned short u16;
typedef unsigned int   u32;
typedef __attribute__((ext_vector_type(8))) short bfrag;   // 8 bf16 = 4 VGPRs
typedef __attribute__((ext_vector_type(4))) float ffrag;   // 4 fp32 acc

__device__ __forceinline__ u16 f2bf(float f) {
  u32 u = __float_as_uint(f);
  u = (u + 0x7fffu + ((u >> 16) & 1u)) >> 16;   // RNE
  return (u16)u;
}
__device__ __forceinline__ float bf2f(u16 v) {
  return __uint_as_float(((u32)v) << 16);
}

// ---------------------------------------------------------------------------
// Kernel 1: reduce Wk over heads -> Wkr (768x64), bkr (64)
__global__ __launch_bounds__(256) void wkr_kernel(
    const float* __restrict__ Wk, const float* __restrict__ bk,
    float* __restrict__ Wkr, float* __restrict__ bkr) {
  int idx = blockIdx.x * 256 + threadIdx.x;   // 0..49151
  int d = idx >> 6, j = idx & 63;
  float s = 0.f;
  #pragma unroll
  for (int h = 0; h < HH; ++h) s += Wk[(size_t)d * DD + h * DHH + j];
  Wkr[idx] = s * (1.f / 12.f);
  if (idx < 64) {
    float sb = 0.f;
    #pragma unroll
    for (int h = 0; h < HH; ++h) sb += bk[h * DHH + idx];
    bkr[idx] = sb * (1.f / 12.f);
  }
}

// ---------------------------------------------------------------------------
// fp32 GEMM (kept for the decision-critical metric): C = A @ W + bias
// BM=BN=64, BK=32, 256 threads, 4x4 microtile.
__global__ __launch_bounds__(256) void gemm_f32_kernel(
    const float* __restrict__ A, const float* __restrict__ W,
    const float* __restrict__ bias, float* __restrict__ C,
    int M, int N, int K) {
  __shared__ float As[32][68];
  __shared__ float Ws[32][68];
  const int t  = threadIdx.x;
  const int m0 = blockIdx.x * 64;
  const int n0 = blockIdx.y * 64;
  const int tx = t & 15, ty = t >> 4;
  const int a_kk = t & 31;
  const int a_m0 = t >> 5;
  const int w_n  = t & 63;
  const int w_k0 = t >> 6;

  float4 acc[4];
  #pragma unroll
  for (int i = 0; i < 4; ++i) acc[i] = make_float4(0.f, 0.f, 0.f, 0.f);

  for (int k0 = 0; k0 < K; k0 += 32) {
    #pragma unroll
    for (int l = 0; l < 8; ++l) {
      int m = a_m0 + 8 * l;
      As[a_kk][m] = A[(size_t)(m0 + m) * K + k0 + a_kk];
    }
    #pragma unroll
    for (int l = 0; l < 8; ++l) {
      int kk = w_k0 * 8 + l;
      Ws[kk][w_n] = W[(size_t)(k0 + kk) * N + n0 + w_n];
    }
    __syncthreads();
    #pragma unroll
    for (int kk = 0; kk < 32; ++kk) {
      float4 a4 = *(const float4*)&As[kk][ty * 4];
      float4 w4 = *(const float4*)&Ws[kk][tx * 4];
      acc[0].x += a4.x * w4.x; acc[0].y += a4.x * w4.y; acc[0].z += a4.x * w4.z; acc[0].w += a4.x * w4.w;
      acc[1].x += a4.y * w4.x; acc[1].y += a4.y * w4.y; acc[1].z += a4.y * w4.z; acc[1].w += a4.y * w4.w;
      acc[2].x += a4.z * w4.x; acc[2].y += a4.z * w4.y; acc[2].z += a4.z * w4.z; acc[2].w += a4.z * w4.w;
      acc[3].x += a4.w * w4.x; acc[3].y += a4.w * w4.y; acc[3].z += a4.w * w4.z; acc[3].w += a4.w * w4.w;
    }
    __syncthreads();
  }
  const float4 b4 = *(const float4*)&bias[n0 + tx * 4];
  #pragma unroll
  for (int i = 0; i < 4; ++i) {
    size_t off = (size_t)(m0 + ty * 4 + i) * N + n0 + tx * 4;
    float4 v = acc[i];
    v.x += b4.x; v.y += b4.y; v.z += b4.z; v.w += b4.w;
    *(float4*)&C[off] = v;
  }
}

// ---------------------------------------------------------------------------
// Weight convert+transpose: W (KxN fp32, K=N=768) -> WT (NxK bf16).
// 64x64 LDS tile transpose; blockIdx.z selects which of 4 weights.
__global__ __launch_bounds__(256) void wconv_kernel(
    const float* __restrict__ W0, const float* __restrict__ W1,
    const float* __restrict__ W2, const float* __restrict__ W3,
    u16* __restrict__ T0, u16* __restrict__ T1,
    u16* __restrict__ T2, u16* __restrict__ T3) {
  __shared__ float tile[64][65];
  int wi = blockIdx.z;
  const float* W = (wi == 0) ? W0 : (wi == 1) ? W1 : (wi == 2) ? W2 : W3;
  u16* T = (wi == 0) ? T0 : (wi == 1) ? T1 : (wi == 2) ? T2 : T3;
  int k0 = blockIdx.x * 64, n0 = blockIdx.y * 64;
  int t = threadIdx.x;
  int r = t >> 2, c4 = (t & 3) * 16;
  #pragma unroll
  for (int j = 0; j < 16; j += 4) {
    float4 v = *(const float4*)&W[(size_t)(k0 + r) * DD + n0 + c4 + j];
    tile[r][c4 + j] = v.x; tile[r][c4 + j + 1] = v.y;
    tile[r][c4 + j + 2] = v.z; tile[r][c4 + j + 3] = v.w;
  }
  __syncthreads();
  #pragma unroll
  for (int j = 0; j < 16; j += 2) {
    u32 p = (u32)f2bf(tile[c4 + j][r]) | ((u32)f2bf(tile[c4 + j + 1][r]) << 16);
    *(u32*)&T[(size_t)(n0 + r) * DD + k0 + c4 + j] = p;
  }
}

// ---------------------------------------------------------------------------
// bf16 MFMA GEMM: C(MxN) = A(MxK bf16) @ BT(NxK bf16)^T + bias (+Res fp32)
// BM=BN=128, BK=32, 256 threads = 4 waves (2x2), wave tile 64x64 via 4x4
// grid of 16x16x32 MFMA. LDS rows padded to 40 u16 (80 B) -> fragment
// ds_read_b128 is 2-way-conflict only (free, m136).
template <bool OUT_BF16, bool ADD_RES>
__global__ __launch_bounds__(256) void mfma_gemm_kernel(
    const u16* __restrict__ A, const u16* __restrict__ BT,
    const float* __restrict__ bias, const float* __restrict__ Res,
    float* __restrict__ Cf, u16* __restrict__ Cb,
    int M, int N, int K) {
  __shared__ u16 Als[128 * 40];
  __shared__ u16 Bls[128 * 40];
  const int t  = threadIdx.x;
  const int m0 = blockIdx.x * 128;
  const int n0 = blockIdx.y * 128;
  const int lane = t & 63;
  const int w  = t >> 6;
  const int wm = w & 1, wn = w >> 1;
  const int q  = lane >> 4;      // quad
  const int lr = lane & 15;

  const int sm = t >> 1;         // staging row 0..127
  const int sh = t & 1;          // which 16-elem half of the 32-wide row
  const u16* gA = A  + (size_t)(m0 + sm) * K + sh * 16;
  const u16* gB = BT + (size_t)(n0 + sm) * K + sh * 16;
  u16* lA = &Als[sm * 40 + sh * 16];
  u16* lB = &Bls[sm * 40 + sh * 16];

  ffrag acc[4][4];
  #pragma unroll
  for (int i = 0; i < 4; ++i)
    #pragma unroll
    for (int j = 0; j < 4; ++j) {
      acc[i][j].x = 0.f; acc[i][j].y = 0.f; acc[i][j].z = 0.f; acc[i][j].w = 0.f;
    }

  for (int k0 = 0; k0 < K; k0 += 32) {
    bfrag av0 = *(const bfrag*)(gA + k0);
    bfrag av1 = *(const bfrag*)(gA + k0 + 8);
    bfrag bv0 = *(const bfrag*)(gB + k0);
    bfrag bv1 = *(const bfrag*)(gB + k0 + 8);
    __syncthreads();              // prior iter's fragment reads complete
    *(bfrag*)lA = av0; *(bfrag*)(lA + 8) = av1;
    *(bfrag*)lB = bv0; *(bfrag*)(lB + 8) = bv1;
    __syncthreads();

    bfrag af[4], bfv[4];
    #pragma unroll
    for (int mi = 0; mi < 4; ++mi)
      af[mi] = *(const bfrag*)&Als[(wm * 64 + mi * 16 + lr) * 40 + q * 8];
    #pragma unroll
    for (int ni = 0; ni < 4; ++ni)
      bfv[ni] = *(const bfrag*)&Bls[(wn * 64 + ni * 16 + lr) * 40 + q * 8];
    #pragma unroll
    for (int mi = 0; mi < 4; ++mi)
      #pragma unroll
      for (int ni = 0; ni < 4; ++ni)
        acc[mi][ni] = __builtin_amdgcn_mfma_f32_16x16x32_bf16(
            af[mi], bfv[ni], acc[mi][ni], 0, 0, 0);
  }

  float bv[4];
  #pragma unroll
  for (int ni = 0; ni < 4; ++ni)
    bv[ni] = bias[n0 + wn * 64 + ni * 16 + lr];

  #pragma unroll
  for (int mi = 0; mi < 4; ++mi) {
    #pragma unroll
    for (int ni = 0; ni < 4; ++ni) {
      int gcol = n0 + wn * 64 + ni * 16 + lr;
      #pragma unroll
      for (int r = 0; r < 4; ++r) {
        int grow = m0 + wm * 64 + mi * 16 + q * 4 + r;
        size_t off = (size_t)grow * N + gcol;
        float v = acc[mi][ni][r] + bv[ni];
        if (ADD_RES) v += Res[off];
        if (OUT_BF16) Cb[off] = f2bf(v);
        else          Cf[off] = v;
      }
    }
  }
}

// ---------------------------------------------------------------------------
// Kernel 3: per-batch bipartite soft matching indices (fp32, exact).
__global__ __launch_bounds__(256) void tome_kernel(
    const float* __restrict__ metric, int* __restrict__ order_g,
    int* __restrict__ dst_g) {
  __shared__ float sm[TSRC * 64];
  int b = blockIdx.x, i = threadIdx.x;
  const float* Mb = metric + (size_t)b * TT * 64;

  float areg[64];
  float na = 0.f;
  #pragma unroll
  for (int d = 0; d < 64; ++d) {
    float v = Mb[(size_t)(2 * i) * 64 + d];
    areg[d] = v; na += v * v;
  }
  float ia = 1.f / (sqrtf(na) + 1e-6f);
  #pragma unroll
  for (int d = 0; d < 64; ++d) areg[d] *= ia;

  float nb = 0.f;
  #pragma unroll
  for (int d = 0; d < 64; ++d) {
    float v = Mb[(size_t)(2 * i + 1) * 64 + d];
    sm[i * 64 + d] = v; nb += v * v;
  }
  float ib = 1.f / (sqrtf(nb) + 1e-6f);
  #pragma unroll
  for (int d = 0; d < 64; ++d) sm[i * 64 + d] *= ib;
  __syncthreads();

  float best = -INFINITY; int besti = 0;
  for (int c = 0; c < TSRC; ++c) {
    float s = 0.f;
    #pragma unroll
    for (int d = 0; d < 64; ++d) s += areg[d] * sm[c * 64 + d];
    if (s > best) { best = s; besti = c; }
  }
  if (i == 0) best = -INFINITY;
  __syncthreads();

  sm[i] = best;
  int* smi = (int*)(sm + TSRC);
  smi[i] = besti;
  __syncthreads();

  float ki = sm[i];
  int r = 0;
  for (int j = 0; j < TSRC; ++j) {
    float kj = sm[j];
    if (kj > ki || (kj == ki && j < i)) ++r;
  }
  int* ord = smi + TSRC;
  ord[r] = i;
  __syncthreads();

  order_g[b * TSRC + i] = ord[i];
  if (i < RR) dst_g[b * RR + i] = smi[ord[i]];
}

// ---------------------------------------------------------------------------
// Kernel 4: merge X -> Xm (fp32 residual) + Xm_bf (bf16 GEMM operand).
__global__ __launch_bounds__(256) void merge_kernel(
    const float* __restrict__ X, const int* __restrict__ order,
    const int* __restrict__ dsti, float* __restrict__ Xm,
    u16* __restrict__ Xmb) {
  int row = blockIdx.x;
  int b = row / TM, t2 = row % TM;
  int c = threadIdx.x;
  const float* Xb = X + (size_t)b * TT * DD;
  float out[3];
  if (t2 < UNM) {
    int tok = 2 * order[b * TSRC + RR + t2];
    #pragma unroll
    for (int l = 0; l < 3; ++l) out[l] = Xb[(size_t)tok * DD + c + 256 * l];
  } else {
    int j = t2 - UNM;
    float cnt = 1.f;
    #pragma unroll
    for (int l = 0; l < 3; ++l) out[l] = Xb[(size_t)(2 * j + 1) * DD + c + 256 * l];
    for (int m = 0; m < RR; ++m) {
      if (dsti[b * RR + m] == j) {
        int tok = 2 * order[b * TSRC + m];
        #pragma unroll
        for (int l = 0; l < 3; ++l) out[l] += Xb[(size_t)tok * DD + c + 256 * l];
        cnt += 1.f;
      }
    }
    float inv = 1.f / cnt;
    #pragma unroll
    for (int l = 0; l < 3; ++l) out[l] *= inv;
  }
  #pragma unroll
  for (int l = 0; l < 3; ++l) {
    Xm[(size_t)row * DD + c + 256 * l]  = out[l];
    Xmb[(size_t)row * DD + c + 256 * l] = f2bf(out[l]);
  }
}

// ---------------------------------------------------------------------------
// Kernel 5: flash-style attention. bf16 in (Q/K/V), bf16 out (ctx), fp32 math.
// Block = (b,h,q-tile 64). Thread t -> q-row (t>>2), k-interleave cg=(t&3):
// simultaneous K-row reads are consecutive -> conflict-free (R2 fix).
// NOTE: ctx may alias Q — Q fully register-staged before any ctx write, and
// each block writes exactly the (rows, head-cols) region it staged.
#define NQT 8
__global__ __launch_bounds__(256) void attn_kernel(
    const u16* __restrict__ Q, const u16* __restrict__ K,
    const u16* __restrict__ V, u16* __restrict__ ctx) {
  __shared__ float Ks[64][68];
  __shared__ float Vs[64][68];
  __shared__ float QP[64][68];

  int blk = blockIdx.x;
  int qt = blk % NQT;
  int bh = blk / NQT;
  int h = bh % HH, b = bh / HH;
  const int t = threadIdx.x;
  int q0 = qt * 64;
  const size_t base = (size_t)b * TM * DD + (size_t)h * DHH;

  int dcol = t & 63, rgrp = t >> 6;
  #pragma unroll
  for (int l = 0; l < 16; ++l) {
    int qi = rgrp * 16 + l;
    int row = q0 + qi;
    QP[qi][dcol] = (row < TM) ? bf2f(Q[base + (size_t)row * DD + dcol]) : 0.f;
  }
  __syncthreads();
  const int qi = t >> 2;
  const int cg = t & 3;
  float4 qreg[16];
  #pragma unroll
  for (int d4 = 0; d4 < 16; ++d4) qreg[d4] = *(const float4*)&QP[qi][d4 * 4];
  __syncthreads();

  float m_i = -INFINITY, l_i = 0.f;
  float4 o[4];
  #pragma unroll
  for (int j = 0; j < 4; ++j) o[j] = make_float4(0.f, 0.f, 0.f, 0.f);

  for (int kt = 0; kt < NQT; ++kt) {
    int k0 = kt * 64;
    int kn = TM - k0; if (kn > 64) kn = 64;
    __syncthreads();
    #pragma unroll
    for (int l = 0; l < 16; ++l) {
      int kk = rgrp * 16 + l;
      int row = k0 + kk;
      float kv = 0.f, vv = 0.f;
      if (row < TM) {
        kv = bf2f(K[base + (size_t)row * DD + dcol]);
        vv = bf2f(V[base + (size_t)row * DD + dcol]);
      }
      Ks[kk][dcol] = kv;
      Vs[kk][dcol] = vv;
    }
    __syncthreads();

    float s[16];
    #pragma unroll
    for (int u = 0; u < 16; ++u) s[u] = 0.f;
    #pragma unroll
    for (int d4 = 0; d4 < 16; ++d4) {
      float4 q4 = qreg[d4];
      #pragma unroll
      for (int u = 0; u < 16; ++u) {
        float4 k4 = *(const float4*)&Ks[4 * u + cg][d4 * 4];
        s[u] += q4.x * k4.x + q4.y * k4.y + q4.z * k4.z + q4.w * k4.w;
      }
    }
    float tmax = -INFINITY;
    #pragma unroll
    for (int u = 0; u < 16; ++u) {
      int kk = 4 * u + cg;
      s[u] = (kk < kn) ? s[u] * 0.125f : -INFINITY;
      tmax = fmaxf(tmax, s[u]);
    }
    tmax = fmaxf(tmax, __shfl_xor(tmax, 1));
    tmax = fmaxf(tmax, __shfl_xor(tmax, 2));
    float new_m = fmaxf(m_i, tmax);
    float alpha = (m_i == -INFINITY) ? 0.f : __expf(m_i - new_m);
    float psum = 0.f;
    #pragma unroll
    for (int u = 0; u < 16; ++u) {
      float p = __expf(s[u] - new_m);
      QP[qi][4 * u + cg] = p;
      psum += p;
    }
    psum += __shfl_xor(psum, 1);
    psum += __shfl_xor(psum, 2);
    l_i = l_i * alpha + psum;
    m_i = new_m;
    #pragma unroll
    for (int j = 0; j < 4; ++j) {
      o[j].x *= alpha; o[j].y *= alpha; o[j].z *= alpha; o[j].w *= alpha;
    }
    __syncthreads();

    #pragma unroll
    for (int kk4 = 0; kk4 < 16; ++kk4) {
      float4 p4 = *(const float4*)&QP[qi][kk4 * 4];
      const float* pv = &p4.x;
      #pragma unroll
      for (int c = 0; c < 4; ++c) {
        float p = pv[c];
        #pragma unroll
        for (int j = 0; j < 4; ++j) {
          float4 v4 = *(const float4*)&Vs[kk4 * 4 + c][cg * 16 + 4 * j];
          o[j].x += p * v4.x; o[j].y += p * v4.y; o[j].z += p * v4.z; o[j].w += p * v4.w;
        }
      }
    }
  }

  float inv_l = 1.f / l_i;
  int row = q0 + qi;
  if (row < TM) {
    size_t g = base + (size_t)row * DD + cg * 16;
    #pragma unroll
    for (int j = 0; j < 4; ++j) {
      u32 p0 = (u32)f2bf(o[j].x * inv_l) | ((u32)f2bf(o[j].y * inv_l) << 16);
      u32 p1 = (u32)f2bf(o[j].z * inv_l) | ((u32)f2bf(o[j].w * inv_l) << 16);
      *(u32*)&ctx[g + 4 * j]     = p0;
      *(u32*)&ctx[g + 4 * j + 2] = p1;
    }
  }
}

// ---------------------------------------------------------------------------
// Kernel 7: in-place LayerNorm on d_out rows (768 wide).
__global__ __launch_bounds__(256) void ln_kernel(
    float* __restrict__ Y, const float* __restrict__ g,
    const float* __restrict__ beta) {
  __shared__ float red[4];
  int row = blockIdx.x, t = threadIdx.x;
  size_t baseo = (size_t)row * DD;
  float x[3];
  #pragma unroll
  for (int l = 0; l < 3; ++l) x[l] = Y[baseo + t + 256 * l];
  float s = x[0] + x[1] + x[2];
  #pragma unroll
  for (int off = 32; off > 0; off >>= 1) s += __shfl_down(s, off, 64);
  if ((t & 63) == 0) red[t >> 6] = s;
  __syncthreads();
  float mu = (red[0] + red[1] + red[2] + red[3]) * (1.f / 768.f);
  __syncthreads();
  float d0 = x[0] - mu, d1 = x[1] - mu, d2 = x[2] - mu;
  float sq = d0 * d0 + d1 * d1 + d2 * d2;
  #pragma unroll
  for (int off = 32; off > 0; off >>= 1) sq += __shfl_down(sq, off, 64);
  if ((t & 63) == 0) red[t >> 6] = sq;
  __syncthreads();
  float var = (red[0] + red[1] + red[2] + red[3]) * (1.f / 768.f);
  float inv = rsqrtf(var + 1e-12f);
  #pragma unroll
  for (int l = 0; l < 3; ++l) {
    int c = t + 256 * l;
    Y[baseo + c] = (x[l] - mu) * inv * g[c] + beta[c];
  }
}

// ---------------------------------------------------------------------------
extern "C" void kernel_launch(void* const* d_in, const int* in_sizes, int n_in,
                              void* d_out, int out_size, void* d_ws, size_t ws_size,
                              hipStream_t stream) {
  const float* X    = (const float*)d_in[0];
  const float* Wq   = (const float*)d_in[1];
  const float* bq   = (const float*)d_in[2];
  const float* Wk   = (const float*)d_in[3];
  const float* bk   = (const float*)d_in[4];
  const float* Wv   = (const float*)d_in[5];
  const float* bv   = (const float*)d_in[6];
  const float* Wo   = (const float*)d_in[7];
  const float* bo   = (const float*)d_in[8];
  const float* ln_g = (const float*)d_in[9];
  const float* ln_b = (const float*)d_in[10];
  float* out = (float*)d_out;

  // workspace layout
  const size_t metric_n = (size_t)16384 * 64;          // fp32
  const size_t wkr_n    = (size_t)768 * 64 + 64;       // fp32
  const size_t idx_n    = (size_t)BNUM * TSRC + BNUM * RR;  // int32
  const size_t buf_n    = (size_t)MROW * DD;           // elements
  const size_t w_n      = (size_t)DD * DD;             // 768*768
  const size_t f32_elems = metric_n + wkr_n + idx_n + buf_n;          // fp32 part
  const size_t u16_elems = 4 * buf_n + 4 * w_n;                       // bf16 part
  const size_t needed = f32_elems * 4 + u16_elems * 2;
  if (ws_size < needed) return;

  float* ws = (float*)d_ws;
  float* metric  = ws;
  float* Wkr     = metric + metric_n;
  float* bkr     = Wkr + (size_t)768 * 64;
  int*   order_g = (int*)(bkr + 64);
  int*   dst_g   = order_g + BNUM * TSRC;
  float* Xm      = (float*)(dst_g + BNUM * RR);        // fp32 residual
  u16*   Xmb     = (u16*)(Xm + buf_n);                 // bf16 merged tokens
  u16*   Qmb     = Xmb + buf_n;
  u16*   Kmb     = Qmb + buf_n;
  u16*   Vmb     = Kmb + buf_n;
  u16*   WqT     = Vmb + buf_n;
  u16*   WkT     = WqT + w_n;
  u16*   WvT     = WkT + w_n;
  u16*   WoT     = WvT + w_n;
  u16*   ctxb    = Qmb;   // alias: safe, see attn_kernel note

  // 1. reduce Wk over heads (fp32 — decision-critical path)
  wkr_kernel<<<(768 * 64) / 256, 256, 0, stream>>>(Wk, bk, Wkr, bkr);
  // 1b. weights -> bf16 transposed (NxK)
  wconv_kernel<<<dim3(12, 12, 4), 256, 0, stream>>>(
      Wq, Wk, Wv, Wo, WqT, WkT, WvT, WoT);
  // 2. metric = X @ Wkr + bkr (fp32, exact vs reference decisions)
  gemm_f32_kernel<<<dim3(16384 / 64, 1), 256, 0, stream>>>(
      X, Wkr, bkr, metric, 16384, 64, 768);
  // 3. bipartite indices
  tome_kernel<<<BNUM, 256, 0, stream>>>(metric, order_g, dst_g);
  // 4. merge tokens (fp32 residual + bf16 operand)
  merge_kernel<<<MROW, 256, 0, stream>>>(X, order_g, dst_g, Xm, Xmb);
  // 5. Q/K/V projections, bf16 MFMA, bf16 outputs
  mfma_gemm_kernel<true, false><<<dim3(MROW / 128, DD / 128), 256, 0, stream>>>(
      Xmb, WqT, bq, nullptr, nullptr, Qmb, MROW, DD, DD);
  mfma_gemm_kernel<true, false><<<dim3(MROW / 128, DD / 128), 256, 0, stream>>>(
      Xmb, WkT, bk, nullptr, nullptr, Kmb, MROW, DD, DD);
  mfma_gemm_kernel<true, false><<<dim3(MROW / 128, DD / 128), 256, 0, stream>>>(
      Xmb, WvT, bv, nullptr, nullptr, Vmb, MROW, DD, DD);
  // 6. attention (bf16 I/O, fp32 math; ctx aliases Qmb)
  attn_kernel<<<BNUM * HH * NQT, 256, 0, stream>>>(Qmb, Kmb, Vmb, ctxb);
  // 7. output projection + bias + residual -> d_out (fp32)
  mfma_gemm_kernel<false, true><<<dim3(MROW / 128, DD / 128), 256, 0, stream>>>(
      ctxb, WoT, bo, Xm, out, nullptr, MROW, DD, DD);
  // 8. in-place layernorm
  ln_kernel<<<MROW, 256, 0, stream>>>(out, ln_g, ln_b);
}

// Round 5
// 596.699 us; speedup vs baseline: 4.1918x; 3.2607x over previous
//
#include <hip/hip_runtime.h>
#include <math.h>

#define BNUM 32
#define TT   512
#define DD   768
#define HH   12
#define DHH  64
#define RR   8
#define TSRC 256     // src (even) / dst (odd) token count
#define UNM  248     // unmerged src tokens
#define TM   504     // tokens after merge
#define MROW 16128   // BNUM * TM

typedef unsigned short u16;
typedef unsigned int   u32;
typedef __attribute__((ext_vector_type(8))) short bfrag;   // 8 bf16 = 4 VGPRs
typedef __attribute__((ext_vector_type(4))) float ffrag;   // 4 fp32 acc

__device__ __forceinline__ u16 f2bf(float f) {
  u32 u = __float_as_uint(f);
  u = (u + 0x7fffu + ((u >> 16) & 1u)) >> 16;   // RNE
  return (u16)u;
}
__device__ __forceinline__ float bf2f(u16 v) {
  return __uint_as_float(((u32)v) << 16);
}

// ---------------------------------------------------------------------------
// Kernel 1: reduce Wk over heads -> Wkr (768x64), bkr (64)
__global__ __launch_bounds__(256) void wkr_kernel(
    const float* __restrict__ Wk, const float* __restrict__ bk,
    float* __restrict__ Wkr, float* __restrict__ bkr) {
  int idx = blockIdx.x * 256 + threadIdx.x;   // 0..49151
  int d = idx >> 6, j = idx & 63;
  float s = 0.f;
  #pragma unroll
  for (int h = 0; h < HH; ++h) s += Wk[(size_t)d * DD + h * DHH + j];
  Wkr[idx] = s * (1.f / 12.f);
  if (idx < 64) {
    float sb = 0.f;
    #pragma unroll
    for (int h = 0; h < HH; ++h) sb += bk[h * DHH + idx];
    bkr[idx] = sb * (1.f / 12.f);
  }
}

// ---------------------------------------------------------------------------
// fp32 GEMM (kept for the decision-critical metric): C = A @ W + bias
__global__ __launch_bounds__(256) void gemm_f32_kernel(
    const float* __restrict__ A, const float* __restrict__ W,
    const float* __restrict__ bias, float* __restrict__ C,
    int M, int N, int K) {
  __shared__ float As[32][68];
  __shared__ float Ws[32][68];
  const int t  = threadIdx.x;
  const int m0 = blockIdx.x * 64;
  const int n0 = blockIdx.y * 64;
  const int tx = t & 15, ty = t >> 4;
  const int a_kk = t & 31;
  const int a_m0 = t >> 5;
  const int w_n  = t & 63;
  const int w_k0 = t >> 6;

  float4 acc[4];
  #pragma unroll
  for (int i = 0; i < 4; ++i) acc[i] = make_float4(0.f, 0.f, 0.f, 0.f);

  for (int k0 = 0; k0 < K; k0 += 32) {
    #pragma unroll
    for (int l = 0; l < 8; ++l) {
      int m = a_m0 + 8 * l;
      As[a_kk][m] = A[(size_t)(m0 + m) * K + k0 + a_kk];
    }
    #pragma unroll
    for (int l = 0; l < 8; ++l) {
      int kk = w_k0 * 8 + l;
      Ws[kk][w_n] = W[(size_t)(k0 + kk) * N + n0 + w_n];
    }
    __syncthreads();
    #pragma unroll
    for (int kk = 0; kk < 32; ++kk) {
      float4 a4 = *(const float4*)&As[kk][ty * 4];
      float4 w4 = *(const float4*)&Ws[kk][tx * 4];
      acc[0].x += a4.x * w4.x; acc[0].y += a4.x * w4.y; acc[0].z += a4.x * w4.z; acc[0].w += a4.x * w4.w;
      acc[1].x += a4.y * w4.x; acc[1].y += a4.y * w4.y; acc[1].z += a4.y * w4.z; acc[1].w += a4.y * w4.w;
      acc[2].x += a4.z * w4.x; acc[2].y += a4.z * w4.y; acc[2].z += a4.z * w4.z; acc[2].w += a4.z * w4.w;
      acc[3].x += a4.w * w4.x; acc[3].y += a4.w * w4.y; acc[3].z += a4.w * w4.z; acc[3].w += a4.w * w4.w;
    }
    __syncthreads();
  }
  const float4 b4 = *(const float4*)&bias[n0 + tx * 4];
  #pragma unroll
  for (int i = 0; i < 4; ++i) {
    size_t off = (size_t)(m0 + ty * 4 + i) * N + n0 + tx * 4;
    float4 v = acc[i];
    v.x += b4.x; v.y += b4.y; v.z += b4.z; v.w += b4.w;
    *(float4*)&C[off] = v;
  }
}

// ---------------------------------------------------------------------------
// Weight convert+transpose: W (KxN fp32, K=N=768) -> WT (NxK bf16).
__global__ __launch_bounds__(256) void wconv_kernel(
    const float* __restrict__ W0, const float* __restrict__ W1,
    const float* __restrict__ W2, const float* __restrict__ W3,
    u16* __restrict__ T0, u16* __restrict__ T1,
    u16* __restrict__ T2, u16* __restrict__ T3) {
  __shared__ float tile[64][65];
  int wi = blockIdx.z;
  const float* W = (wi == 0) ? W0 : (wi == 1) ? W1 : (wi == 2) ? W2 : W3;
  u16* T = (wi == 0) ? T0 : (wi == 1) ? T1 : (wi == 2) ? T2 : T3;
  int k0 = blockIdx.x * 64, n0 = blockIdx.y * 64;
  int t = threadIdx.x;
  int r = t >> 2, c4 = (t & 3) * 16;
  #pragma unroll
  for (int j = 0; j < 16; j += 4) {
    float4 v = *(const float4*)&W[(size_t)(k0 + r) * DD + n0 + c4 + j];
    tile[r][c4 + j] = v.x; tile[r][c4 + j + 1] = v.y;
    tile[r][c4 + j + 2] = v.z; tile[r][c4 + j + 3] = v.w;
  }
  __syncthreads();
  #pragma unroll
  for (int j = 0; j < 16; j += 2) {
    u32 p = (u32)f2bf(tile[c4 + j][r]) | ((u32)f2bf(tile[c4 + j + 1][r]) << 16);
    *(u32*)&T[(size_t)(n0 + r) * DD + k0 + c4 + j] = p;
  }
}

// ---------------------------------------------------------------------------
// bf16 MFMA GEMM: C(MxN) = A(MxK bf16) @ BT(NxK bf16)^T + bias (+Res fp32)
template <bool OUT_BF16, bool ADD_RES>
__global__ __launch_bounds__(256) void mfma_gemm_kernel(
    const u16* __restrict__ A, const u16* __restrict__ BT,
    const float* __restrict__ bias, const float* __restrict__ Res,
    float* __restrict__ Cf, u16* __restrict__ Cb,
    int M, int N, int K) {
  __shared__ u16 Als[128 * 40];
  __shared__ u16 Bls[128 * 40];
  const int t  = threadIdx.x;
  const int m0 = blockIdx.x * 128;
  const int n0 = blockIdx.y * 128;
  const int lane = t & 63;
  const int w  = t >> 6;
  const int wm = w & 1, wn = w >> 1;
  const int q  = lane >> 4;
  const int lr = lane & 15;

  const int sm = t >> 1;
  const int sh = t & 1;
  const u16* gA = A  + (size_t)(m0 + sm) * K + sh * 16;
  const u16* gB = BT + (size_t)(n0 + sm) * K + sh * 16;
  u16* lA = &Als[sm * 40 + sh * 16];
  u16* lB = &Bls[sm * 40 + sh * 16];

  ffrag acc[4][4];
  #pragma unroll
  for (int i = 0; i < 4; ++i)
    #pragma unroll
    for (int j = 0; j < 4; ++j) {
      acc[i][j].x = 0.f; acc[i][j].y = 0.f; acc[i][j].z = 0.f; acc[i][j].w = 0.f;
    }

  for (int k0 = 0; k0 < K; k0 += 32) {
    bfrag av0 = *(const bfrag*)(gA + k0);
    bfrag av1 = *(const bfrag*)(gA + k0 + 8);
    bfrag bv0 = *(const bfrag*)(gB + k0);
    bfrag bv1 = *(const bfrag*)(gB + k0 + 8);
    __syncthreads();
    *(bfrag*)lA = av0; *(bfrag*)(lA + 8) = av1;
    *(bfrag*)lB = bv0; *(bfrag*)(lB + 8) = bv1;
    __syncthreads();

    bfrag af[4], bfv[4];
    #pragma unroll
    for (int mi = 0; mi < 4; ++mi)
      af[mi] = *(const bfrag*)&Als[(wm * 64 + mi * 16 + lr) * 40 + q * 8];
    #pragma unroll
    for (int ni = 0; ni < 4; ++ni)
      bfv[ni] = *(const bfrag*)&Bls[(wn * 64 + ni * 16 + lr) * 40 + q * 8];
    #pragma unroll
    for (int mi = 0; mi < 4; ++mi)
      #pragma unroll
      for (int ni = 0; ni < 4; ++ni)
        acc[mi][ni] = __builtin_amdgcn_mfma_f32_16x16x32_bf16(
            af[mi], bfv[ni], acc[mi][ni], 0, 0, 0);
  }

  float bv[4];
  #pragma unroll
  for (int ni = 0; ni < 4; ++ni)
    bv[ni] = bias[n0 + wn * 64 + ni * 16 + lr];

  #pragma unroll
  for (int mi = 0; mi < 4; ++mi) {
    #pragma unroll
    for (int ni = 0; ni < 4; ++ni) {
      int gcol = n0 + wn * 64 + ni * 16 + lr;
      #pragma unroll
      for (int r = 0; r < 4; ++r) {
        int grow = m0 + wm * 64 + mi * 16 + q * 4 + r;
        size_t off = (size_t)grow * N + gcol;
        float v = acc[mi][ni][r] + bv[ni];
        if (ADD_RES) v += Res[off];
        if (OUT_BF16) Cb[off] = f2bf(v);
        else          Cf[off] = v;
      }
    }
  }
}

// ---------------------------------------------------------------------------
// Kernel 3: per-batch bipartite soft matching indices (fp32, exact).
__global__ __launch_bounds__(256) void tome_kernel(
    const float* __restrict__ metric, int* __restrict__ order_g,
    int* __restrict__ dst_g) {
  __shared__ float sm[TSRC * 64];
  int b = blockIdx.x, i = threadIdx.x;
  const float* Mb = metric + (size_t)b * TT * 64;

  float areg[64];
  float na = 0.f;
  #pragma unroll
  for (int d = 0; d < 64; ++d) {
    float v = Mb[(size_t)(2 * i) * 64 + d];
    areg[d] = v; na += v * v;
  }
  float ia = 1.f / (sqrtf(na) + 1e-6f);
  #pragma unroll
  for (int d = 0; d < 64; ++d) areg[d] *= ia;

  float nb = 0.f;
  #pragma unroll
  for (int d = 0; d < 64; ++d) {
    float v = Mb[(size_t)(2 * i + 1) * 64 + d];
    sm[i * 64 + d] = v; nb += v * v;
  }
  float ib = 1.f / (sqrtf(nb) + 1e-6f);
  #pragma unroll
  for (int d = 0; d < 64; ++d) sm[i * 64 + d] *= ib;
  __syncthreads();

  float best = -INFINITY; int besti = 0;
  for (int c = 0; c < TSRC; ++c) {
    float s = 0.f;
    #pragma unroll
    for (int d = 0; d < 64; ++d) s += areg[d] * sm[c * 64 + d];
    if (s > best) { best = s; besti = c; }
  }
  if (i == 0) best = -INFINITY;
  __syncthreads();

  sm[i] = best;
  int* smi = (int*)(sm + TSRC);
  smi[i] = besti;
  __syncthreads();

  float ki = sm[i];
  int r = 0;
  for (int j = 0; j < TSRC; ++j) {
    float kj = sm[j];
    if (kj > ki || (kj == ki && j < i)) ++r;
  }
  int* ord = smi + TSRC;
  ord[r] = i;
  __syncthreads();

  order_g[b * TSRC + i] = ord[i];
  if (i < RR) dst_g[b * RR + i] = smi[ord[i]];
}

// ---------------------------------------------------------------------------
// Kernel 4: merge X -> Xm (fp32 residual) + Xm_bf (bf16 GEMM operand).
__global__ __launch_bounds__(256) void merge_kernel(
    const float* __restrict__ X, const int* __restrict__ order,
    const int* __restrict__ dsti, float* __restrict__ Xm,
    u16* __restrict__ Xmb) {
  int row = blockIdx.x;
  int b = row / TM, t2 = row % TM;
  int c = threadIdx.x;
  const float* Xb = X + (size_t)b * TT * DD;
  float out[3];
  if (t2 < UNM) {
    int tok = 2 * order[b * TSRC + RR + t2];
    #pragma unroll
    for (int l = 0; l < 3; ++l) out[l] = Xb[(size_t)tok * DD + c + 256 * l];
  } else {
    int j = t2 - UNM;
    float cnt = 1.f;
    #pragma unroll
    for (int l = 0; l < 3; ++l) out[l] = Xb[(size_t)(2 * j + 1) * DD + c + 256 * l];
    for (int m = 0; m < RR; ++m) {
      if (dsti[b * RR + m] == j) {
        int tok = 2 * order[b * TSRC + m];
        #pragma unroll
        for (int l = 0; l < 3; ++l) out[l] += Xb[(size_t)tok * DD + c + 256 * l];
        cnt += 1.f;
      }
    }
    float inv = 1.f / cnt;
    #pragma unroll
    for (int l = 0; l < 3; ++l) out[l] *= inv;
  }
  #pragma unroll
  for (int l = 0; l < 3; ++l) {
    Xm[(size_t)row * DD + c + 256 * l]  = out[l];
    Xmb[(size_t)row * DD + c + 256 * l] = f2bf(out[l]);
  }
}

// ---------------------------------------------------------------------------
// Kernel 5: MFMA flash attention. bf16 Q/K/V/ctx, fp32 softmax state.
// Block = (b, h, 64-row q-tile), 256 thr = 4 waves; wave w owns q-rows
// q0+16w..+15. Computes S^T = K·Q^T (A=K rows contiguous, B=Q rows
// contiguous — both direct 16B global reads). S^T C-layout: lane's q-row =
// lane&15 (one row/lane -> softmax = intra-lane + shfl_xor(16,32));
// lane's 4 acc regs = 4 consecutive tokens -> P packs to b64 LDS writes in
// A-operand layout P[q][k]. V transpose-staged to Vt[dim][token] (masked
// tokens -> 0, so no NaN via P*garbage). PV: A=P (b128 LDS), B=Vt (b128).
// NOTE: ctx aliases Q: block reads exactly its own (rows x head-dims)
// region of Q (preloaded) and writes the same region at the end.
#define NQT 8
__global__ __launch_bounds__(256) void attn_kernel(
    const u16* __restrict__ Q, const u16* __restrict__ K,
    const u16* __restrict__ V, u16* __restrict__ ctx) {
  __shared__ u16 Pt[64][72];   // P[q-row][token], 144B rows (16B-aligned)
  __shared__ u16 Vt[64][72];   // V^T [dim][token]

  int blk = blockIdx.x;
  int qt = blk % NQT;
  int bh = blk / NQT;
  int h = bh % HH, b = bh / HH;
  const int t = threadIdx.x;
  const int lane = t & 63, w = t >> 6;
  const int lr = lane & 15, quad = lane >> 4;
  const int q0 = qt * 64;
  const size_t base = (size_t)b * TM * DD + (size_t)h * DHH;

  // Preload Q B-fragments: col n = lr -> q-row q0+16w+lr; k = kh*32+quad*8+j
  bfrag qf[2];
  {
    const u16* qp = Q + base + (size_t)(q0 + 16 * w + lr) * DD + quad * 8;
    qf[0] = *(const bfrag*)(qp);
    qf[1] = *(const bfrag*)(qp + 32);
  }

  float m_i = -INFINITY, l_i = 0.f;   // state for q-row q0+16w+lr
  ffrag o[4];                          // O[q-rows (quad*4+reg)][dims ni*16+lr]
  #pragma unroll
  for (int ni = 0; ni < 4; ++ni) {
    o[ni].x = 0.f; o[ni].y = 0.f; o[ni].z = 0.f; o[ni].w = 0.f;
  }

  const int vd  = t & 63;   // staging: dim
  const int vs0 = t >> 6;   // staging: token-pair base

  for (int kt = 0; kt < NQT; ++kt) {
    const int k0 = kt * 64;
    if (kt) __syncthreads();           // prior Vt fully consumed
    // stage V^T tile (tokens k0..k0+63), masked tokens -> 0
    #pragma unroll
    for (int i = 0; i < 8; ++i) {
      int s = vs0 + 4 * i;
      int tok0 = k0 + 2 * s;
      u16 v0 = (tok0 < TM)     ? V[base + (size_t)tok0 * DD + vd]       : (u16)0;
      u16 v1 = (tok0 + 1 < TM) ? V[base + (size_t)(tok0 + 1) * DD + vd] : (u16)0;
      *(u32*)&Vt[vd][2 * s] = (u32)v0 | ((u32)v1 << 16);
    }
    __syncthreads();

    // S^T tile: acc[mi] covers tokens k0+mi*16+quad*4+reg, q-row lr
    ffrag s4[4];
    #pragma unroll
    for (int mi = 0; mi < 4; ++mi) {
      const u16* kp = K + base + (size_t)(k0 + mi * 16 + lr) * DD + quad * 8;
      bfrag ka0 = *(const bfrag*)(kp);
      bfrag ka1 = *(const bfrag*)(kp + 32);
      ffrag z; z.x = 0.f; z.y = 0.f; z.z = 0.f; z.w = 0.f;
      z = __builtin_amdgcn_mfma_f32_16x16x32_bf16(ka0, qf[0], z, 0, 0, 0);
      s4[mi] = __builtin_amdgcn_mfma_f32_16x16x32_bf16(ka1, qf[1], z, 0, 0, 0);
    }

    // online softmax over lane's 16 scores
    float sc[16];
    float tmax = -INFINITY;
    #pragma unroll
    for (int mi = 0; mi < 4; ++mi)
      #pragma unroll
      for (int r = 0; r < 4; ++r) {
        int tok = k0 + mi * 16 + quad * 4 + r;
        float v = (tok < TM) ? s4[mi][r] * 0.125f : -INFINITY;
        sc[mi * 4 + r] = v;
        tmax = fmaxf(tmax, v);
      }
    tmax = fmaxf(tmax, __shfl_xor(tmax, 16));
    tmax = fmaxf(tmax, __shfl_xor(tmax, 32));
    float nm = fmaxf(m_i, tmax);       // finite: every k-tile has valid tokens
    float alpha = __expf(m_i - nm);    // first tile: exp(-inf)=0
    float psum = 0.f;
    u16 pb[16];
    #pragma unroll
    for (int i = 0; i < 16; ++i) {
      float p = __expf(sc[i] - nm);
      psum += p;
      pb[i] = f2bf(p);
    }
    psum += __shfl_xor(psum, 16);
    psum += __shfl_xor(psum, 32);
    l_i = l_i * alpha + psum;
    m_i = nm;

    // write P rows (wave-private): row 16w+lr, cols mi*16+quad*4..+3
    #pragma unroll
    for (int mi = 0; mi < 4; ++mi) {
      u32 lo = (u32)pb[mi * 4 + 0] | ((u32)pb[mi * 4 + 1] << 16);
      u32 hi = (u32)pb[mi * 4 + 2] | ((u32)pb[mi * 4 + 3] << 16);
      u32* dst = (u32*)&Pt[16 * w + lr][mi * 16 + quad * 4];
      dst[0] = lo; dst[1] = hi;
    }

    // rescale O by alpha of its rows (row = quad*4+reg -> alpha from lane r)
    float al[4];
    #pragma unroll
    for (int r = 0; r < 4; ++r) al[r] = __shfl(alpha, quad * 4 + r);
    #pragma unroll
    for (int ni = 0; ni < 4; ++ni)
      #pragma unroll
      for (int r = 0; r < 4; ++r) o[ni][r] *= al[r];

    // PV: A = P[16w+lr][token chunk], B = Vt[dim][token chunk]
    bfrag pa0 = *(const bfrag*)&Pt[16 * w + lr][quad * 8];
    bfrag pa1 = *(const bfrag*)&Pt[16 * w + lr][32 + quad * 8];
    #pragma unroll
    for (int ni = 0; ni < 4; ++ni) {
      bfrag vb0 = *(const bfrag*)&Vt[ni * 16 + lr][quad * 8];
      bfrag vb1 = *(const bfrag*)&Vt[ni * 16 + lr][32 + quad * 8];
      o[ni] = __builtin_amdgcn_mfma_f32_16x16x32_bf16(pa0, vb0, o[ni], 0, 0, 0);
      o[ni] = __builtin_amdgcn_mfma_f32_16x16x32_bf16(pa1, vb1, o[ni], 0, 0, 0);
    }
  }

  // epilogue: O /= l, store bf16
  float invl[4];
  #pragma unroll
  for (int r = 0; r < 4; ++r) {
    float lv = __shfl(l_i, quad * 4 + r);
    invl[r] = 1.f / lv;
  }
  #pragma unroll
  for (int r = 0; r < 4; ++r) {
    int row = q0 + 16 * w + quad * 4 + r;
    if (row < TM) {
      size_t g = base + (size_t)row * DD + lr;
      #pragma unroll
      for (int ni = 0; ni < 4; ++ni)
        ctx[g + ni * 16] = f2bf(o[ni][r] * invl[r]);
    }
  }
}

// ---------------------------------------------------------------------------
// Kernel 7: in-place LayerNorm on d_out rows (768 wide).
__global__ __launch_bounds__(256) void ln_kernel(
    float* __restrict__ Y, const float* __restrict__ g,
    const float* __restrict__ beta) {
  __shared__ float red[4];
  int row = blockIdx.x, t = threadIdx.x;
  size_t baseo = (size_t)row * DD;
  float x[3];
  #pragma unroll
  for (int l = 0; l < 3; ++l) x[l] = Y[baseo + t + 256 * l];
  float s = x[0] + x[1] + x[2];
  #pragma unroll
  for (int off = 32; off > 0; off >>= 1) s += __shfl_down(s, off, 64);
  if ((t & 63) == 0) red[t >> 6] = s;
  __syncthreads();
  float mu = (red[0] + red[1] + red[2] + red[3]) * (1.f / 768.f);
  __syncthreads();
  float d0 = x[0] - mu, d1 = x[1] - mu, d2 = x[2] - mu;
  float sq = d0 * d0 + d1 * d1 + d2 * d2;
  #pragma unroll
  for (int off = 32; off > 0; off >>= 1) sq += __shfl_down(sq, off, 64);
  if ((t & 63) == 0) red[t >> 6] = sq;
  __syncthreads();
  float var = (red[0] + red[1] + red[2] + red[3]) * (1.f / 768.f);
  float inv = rsqrtf(var + 1e-12f);
  #pragma unroll
  for (int l = 0; l < 3; ++l) {
    int c = t + 256 * l;
    Y[baseo + c] = (x[l] - mu) * inv * g[c] + beta[c];
  }
}

// ---------------------------------------------------------------------------
extern "C" void kernel_launch(void* const* d_in, const int* in_sizes, int n_in,
                              void* d_out, int out_size, void* d_ws, size_t ws_size,
                              hipStream_t stream) {
  const float* X    = (const float*)d_in[0];
  const float* Wq   = (const float*)d_in[1];
  const float* bq   = (const float*)d_in[2];
  const float* Wk   = (const float*)d_in[3];
  const float* bk   = (const float*)d_in[4];
  const float* Wv   = (const float*)d_in[5];
  const float* bv   = (const float*)d_in[6];
  const float* Wo   = (const float*)d_in[7];
  const float* bo   = (const float*)d_in[8];
  const float* ln_g = (const float*)d_in[9];
  const float* ln_b = (const float*)d_in[10];
  float* out = (float*)d_out;

  const size_t metric_n = (size_t)16384 * 64;
  const size_t wkr_n    = (size_t)768 * 64 + 64;
  const size_t idx_n    = (size_t)BNUM * TSRC + BNUM * RR;
  const size_t buf_n    = (size_t)MROW * DD;
  const size_t w_n      = (size_t)DD * DD;
  const size_t f32_elems = metric_n + wkr_n + idx_n + buf_n;
  const size_t u16_elems = 4 * buf_n + 4 * w_n;
  const size_t needed = f32_elems * 4 + u16_elems * 2;
  if (ws_size < needed) return;

  float* ws = (float*)d_ws;
  float* metric  = ws;
  float* Wkr     = metric + metric_n;
  float* bkr     = Wkr + (size_t)768 * 64;
  int*   order_g = (int*)(bkr + 64);
  int*   dst_g   = order_g + BNUM * TSRC;
  float* Xm      = (float*)(dst_g + BNUM * RR);
  u16*   Xmb     = (u16*)(Xm + buf_n);
  u16*   Qmb     = Xmb + buf_n;
  u16*   Kmb     = Qmb + buf_n;
  u16*   Vmb     = Kmb + buf_n;
  u16*   WqT     = Vmb + buf_n;
  u16*   WkT     = WqT + w_n;
  u16*   WvT     = WkT + w_n;
  u16*   WoT     = WvT + w_n;
  u16*   ctxb    = Qmb;   // alias: safe, see attn_kernel note

  wkr_kernel<<<(768 * 64) / 256, 256, 0, stream>>>(Wk, bk, Wkr, bkr);
  wconv_kernel<<<dim3(12, 12, 4), 256, 0, stream>>>(
      Wq, Wk, Wv, Wo, WqT, WkT, WvT, WoT);
  gemm_f32_kernel<<<dim3(16384 / 64, 1), 256, 0, stream>>>(
      X, Wkr, bkr, metric, 16384, 64, 768);
  tome_kernel<<<BNUM, 256, 0, stream>>>(metric, order_g, dst_g);
  merge_kernel<<<MROW, 256, 0, stream>>>(X, order_g, dst_g, Xm, Xmb);
  mfma_gemm_kernel<true, false><<<dim3(MROW / 128, DD / 128), 256, 0, stream>>>(
      Xmb, WqT, bq, nullptr, nullptr, Qmb, MROW, DD, DD);
  mfma_gemm_kernel<true, false><<<dim3(MROW / 128, DD / 128), 256, 0, stream>>>(
      Xmb, WkT, bk, nullptr, nullptr, Kmb, MROW, DD, DD);
  mfma_gemm_kernel<true, false><<<dim3(MROW / 128, DD / 128), 256, 0, stream>>>(
      Xmb, WvT, bv, nullptr, nullptr, Vmb, MROW, DD, DD);
  attn_kernel<<<BNUM * HH * NQT, 256, 0, stream>>>(Qmb, Kmb, Vmb, ctxb);
  mfma_gemm_kernel<false, true><<<dim3(MROW / 128, DD / 128), 256, 0, stream>>>(
      ctxb, WoT, bo, Xm, out, nullptr, MROW, DD, DD);
  ln_kernel<<<MROW, 256, 0, stream>>>(out, ln_g, ln_b);
}

// Round 6
// 578.127 us; speedup vs baseline: 4.3265x; 1.0321x over previous
//
#include <hip/hip_runtime.h>
#include <math.h>

#define BNUM 32
#define TT   512
#define DD   768
#define HH   12
#define DHH  64
#define RR   8
#define TSRC 256     // src (even) / dst (odd) token count
#define UNM  248     // unmerged src tokens
#define TM   504     // tokens after merge
#define MROW 16128   // BNUM * TM

typedef unsigned short u16;
typedef unsigned int   u32;
typedef __attribute__((ext_vector_type(8))) short bfrag;   // 8 bf16 = 4 VGPRs
typedef __attribute__((ext_vector_type(4))) float ffrag;   // 4 fp32 acc

__device__ __forceinline__ u16 f2bf(float f) {
  u32 u = __float_as_uint(f);
  u = (u + 0x7fffu + ((u >> 16) & 1u)) >> 16;   // RNE
  return (u16)u;
}
__device__ __forceinline__ float bf2f(u16 v) {
  return __uint_as_float(((u32)v) << 16);
}

// ---------------------------------------------------------------------------
// Kernel 1: reduce Wk over heads -> Wkr (768x64), bkr (64)
__global__ __launch_bounds__(256) void wkr_kernel(
    const float* __restrict__ Wk, const float* __restrict__ bk,
    float* __restrict__ Wkr, float* __restrict__ bkr) {
  int idx = blockIdx.x * 256 + threadIdx.x;   // 0..49151
  int d = idx >> 6, j = idx & 63;
  float s = 0.f;
  #pragma unroll
  for (int h = 0; h < HH; ++h) s += Wk[(size_t)d * DD + h * DHH + j];
  Wkr[idx] = s * (1.f / 12.f);
  if (idx < 64) {
    float sb = 0.f;
    #pragma unroll
    for (int h = 0; h < HH; ++h) sb += bk[h * DHH + idx];
    bkr[idx] = sb * (1.f / 12.f);
  }
}

// ---------------------------------------------------------------------------
// fp32 GEMM for the decision-critical metric. BM=32, BN=64(==N), BK=32.
// 512 blocks (2/CU, 8 waves/CU) + register prefetch pipeline.
__global__ __launch_bounds__(256) void gemm_f32_kernel(
    const float* __restrict__ A, const float* __restrict__ W,
    const float* __restrict__ bias, float* __restrict__ C,
    int M, int N, int K) {
  __shared__ float As[32][34];   // [kk][m], stride 34 dw: 2-way writes (free)
  __shared__ float Ws[32][66];   // [kk][n], stride 66 dw: conflict-free f4 reads
  const int t  = threadIdx.x;
  const int m0 = blockIdx.x * 32;
  const int tx = t & 15, ty = t >> 4;    // out: rows ty*2..+1, cols tx*4..+3
  const int a_kk = t & 31;
  const int a_m  = t >> 5;               // rows a_m + 8l, l=0..3
  const int w_n  = t & 63;
  const int w_k0 = t >> 6;               // kks w_k0*8 + l, l=0..7

  float a_pre[4], w_pre[8];
  #pragma unroll
  for (int l = 0; l < 4; ++l)
    a_pre[l] = A[(size_t)(m0 + a_m + 8 * l) * K + a_kk];
  #pragma unroll
  for (int l = 0; l < 8; ++l)
    w_pre[l] = W[(size_t)(w_k0 * 8 + l) * N + w_n];

  float4 acc0 = make_float4(0.f, 0.f, 0.f, 0.f);
  float4 acc1 = make_float4(0.f, 0.f, 0.f, 0.f);

  for (int k0 = 0; k0 < K; k0 += 32) {
    __syncthreads();
    #pragma unroll
    for (int l = 0; l < 4; ++l) As[a_kk][a_m + 8 * l] = a_pre[l];
    #pragma unroll
    for (int l = 0; l < 8; ++l) Ws[w_k0 * 8 + l][w_n] = w_pre[l];
    __syncthreads();
    if (k0 + 32 < K) {   // prefetch next tile (hides latency behind compute)
      #pragma unroll
      for (int l = 0; l < 4; ++l)
        a_pre[l] = A[(size_t)(m0 + a_m + 8 * l) * K + k0 + 32 + a_kk];
      #pragma unroll
      for (int l = 0; l < 8; ++l)
        w_pre[l] = W[(size_t)(k0 + 32 + w_k0 * 8 + l) * N + w_n];
    }
    #pragma unroll
    for (int kk = 0; kk < 32; ++kk) {
      float2 a2 = *(const float2*)&As[kk][ty * 2];
      float4 w4 = *(const float4*)&Ws[kk][tx * 4];
      acc0.x += a2.x * w4.x; acc0.y += a2.x * w4.y; acc0.z += a2.x * w4.z; acc0.w += a2.x * w4.w;
      acc1.x += a2.y * w4.x; acc1.y += a2.y * w4.y; acc1.z += a2.y * w4.z; acc1.w += a2.y * w4.w;
    }
  }
  const float4 b4 = *(const float4*)&bias[tx * 4];
  float4 v0 = acc0, v1 = acc1;
  v0.x += b4.x; v0.y += b4.y; v0.z += b4.z; v0.w += b4.w;
  v1.x += b4.x; v1.y += b4.y; v1.z += b4.z; v1.w += b4.w;
  *(float4*)&C[(size_t)(m0 + ty * 2) * N + tx * 4]     = v0;
  *(float4*)&C[(size_t)(m0 + ty * 2 + 1) * N + tx * 4] = v1;
}

// ---------------------------------------------------------------------------
// Weight convert+transpose: W (KxN fp32, K=N=768) -> WT (NxK bf16).
__global__ __launch_bounds__(256) void wconv_kernel(
    const float* __restrict__ W0, const float* __restrict__ W1,
    const float* __restrict__ W2, const float* __restrict__ W3,
    u16* __restrict__ T0, u16* __restrict__ T1,
    u16* __restrict__ T2, u16* __restrict__ T3) {
  __shared__ float tile[64][65];
  int wi = blockIdx.z;
  const float* W = (wi == 0) ? W0 : (wi == 1) ? W1 : (wi == 2) ? W2 : W3;
  u16* T = (wi == 0) ? T0 : (wi == 1) ? T1 : (wi == 2) ? T2 : T3;
  int k0 = blockIdx.x * 64, n0 = blockIdx.y * 64;
  int t = threadIdx.x;
  int r = t >> 2, c4 = (t & 3) * 16;
  #pragma unroll
  for (int j = 0; j < 16; j += 4) {
    float4 v = *(const float4*)&W[(size_t)(k0 + r) * DD + n0 + c4 + j];
    tile[r][c4 + j] = v.x; tile[r][c4 + j + 1] = v.y;
    tile[r][c4 + j + 2] = v.z; tile[r][c4 + j + 3] = v.w;
  }
  __syncthreads();
  #pragma unroll
  for (int j = 0; j < 16; j += 2) {
    u32 p = (u32)f2bf(tile[c4 + j][r]) | ((u32)f2bf(tile[c4 + j + 1][r]) << 16);
    *(u32*)&T[(size_t)(n0 + r) * DD + k0 + c4 + j] = p;
  }
}

// ---------------------------------------------------------------------------
// bf16 MFMA GEMM: C(MxN) = A(MxK bf16) @ BT(NxK bf16)^T + bias (+Res fp32)
// BM=BN=128, BK=32, prefetch-pipelined staging. ROW_BIAS: bias indexed by
// output ROW (for the V^T GEMM where rows are output dims).
template <bool OUT_BF16, bool ADD_RES, bool ROW_BIAS>
__global__ __launch_bounds__(256) void mfma_gemm_kernel(
    const u16* __restrict__ A, const u16* __restrict__ BT,
    const float* __restrict__ bias, const float* __restrict__ Res,
    float* __restrict__ Cf, u16* __restrict__ Cb,
    int M, int N, int K) {
  __shared__ u16 Als[128 * 40];
  __shared__ u16 Bls[128 * 40];
  const int t  = threadIdx.x;
  const int m0 = blockIdx.x * 128;
  const int n0 = blockIdx.y * 128;
  const int lane = t & 63;
  const int w  = t >> 6;
  const int wm = w & 1, wn = w >> 1;
  const int q  = lane >> 4;
  const int lr = lane & 15;

  const int sm = t >> 1;
  const int sh = t & 1;
  const u16* gA = A  + (size_t)(m0 + sm) * K + sh * 16;
  const u16* gB = BT + (size_t)(n0 + sm) * K + sh * 16;
  u16* lA = &Als[sm * 40 + sh * 16];
  u16* lB = &Bls[sm * 40 + sh * 16];

  ffrag acc[4][4];
  #pragma unroll
  for (int i = 0; i < 4; ++i)
    #pragma unroll
    for (int j = 0; j < 4; ++j) {
      acc[i][j].x = 0.f; acc[i][j].y = 0.f; acc[i][j].z = 0.f; acc[i][j].w = 0.f;
    }

  bfrag av0 = *(const bfrag*)(gA);
  bfrag av1 = *(const bfrag*)(gA + 8);
  bfrag bv0 = *(const bfrag*)(gB);
  bfrag bv1 = *(const bfrag*)(gB + 8);

  for (int k0 = 0; k0 < K; k0 += 32) {
    __syncthreads();              // prior iter's fragment reads complete
    *(bfrag*)lA = av0; *(bfrag*)(lA + 8) = av1;
    *(bfrag*)lB = bv0; *(bfrag*)(lB + 8) = bv1;
    __syncthreads();
    if (k0 + 32 < K) {            // prefetch next staging tile early
      av0 = *(const bfrag*)(gA + k0 + 32);
      av1 = *(const bfrag*)(gA + k0 + 40);
      bv0 = *(const bfrag*)(gB + k0 + 32);
      bv1 = *(const bfrag*)(gB + k0 + 40);
    }

    bfrag af[4], bfv[4];
    #pragma unroll
    for (int mi = 0; mi < 4; ++mi)
      af[mi] = *(const bfrag*)&Als[(wm * 64 + mi * 16 + lr) * 40 + q * 8];
    #pragma unroll
    for (int ni = 0; ni < 4; ++ni)
      bfv[ni] = *(const bfrag*)&Bls[(wn * 64 + ni * 16 + lr) * 40 + q * 8];
    #pragma unroll
    for (int mi = 0; mi < 4; ++mi)
      #pragma unroll
      for (int ni = 0; ni < 4; ++ni)
        acc[mi][ni] = __builtin_amdgcn_mfma_f32_16x16x32_bf16(
            af[mi], bfv[ni], acc[mi][ni], 0, 0, 0);
  }

  float bcol[4];
  if (!ROW_BIAS) {
    #pragma unroll
    for (int ni = 0; ni < 4; ++ni)
      bcol[ni] = bias[n0 + wn * 64 + ni * 16 + lr];
  }

  #pragma unroll
  for (int mi = 0; mi < 4; ++mi) {
    #pragma unroll
    for (int ni = 0; ni < 4; ++ni) {
      int gcol = n0 + wn * 64 + ni * 16 + lr;
      #pragma unroll
      for (int r = 0; r < 4; ++r) {
        int grow = m0 + wm * 64 + mi * 16 + q * 4 + r;
        size_t off = (size_t)grow * N + gcol;
        float v = acc[mi][ni][r];
        v += ROW_BIAS ? bias[grow] : bcol[ni];
        if (ADD_RES) v += Res[off];
        if (OUT_BF16) Cb[off] = f2bf(v);
        else          Cf[off] = v;
      }
    }
  }
}

// ---------------------------------------------------------------------------
// Kernel 3: per-batch bipartite soft matching indices (fp32, exact).
__global__ __launch_bounds__(256) void tome_kernel(
    const float* __restrict__ metric, int* __restrict__ order_g,
    int* __restrict__ dst_g) {
  __shared__ float sm[TSRC * 64];
  int b = blockIdx.x, i = threadIdx.x;
  const float* Mb = metric + (size_t)b * TT * 64;

  float areg[64];
  float na = 0.f;
  #pragma unroll
  for (int d = 0; d < 64; ++d) {
    float v = Mb[(size_t)(2 * i) * 64 + d];
    areg[d] = v; na += v * v;
  }
  float ia = 1.f / (sqrtf(na) + 1e-6f);
  #pragma unroll
  for (int d = 0; d < 64; ++d) areg[d] *= ia;

  float nb = 0.f;
  #pragma unroll
  for (int d = 0; d < 64; ++d) {
    float v = Mb[(size_t)(2 * i + 1) * 64 + d];
    sm[i * 64 + d] = v; nb += v * v;
  }
  float ib = 1.f / (sqrtf(nb) + 1e-6f);
  #pragma unroll
  for (int d = 0; d < 64; ++d) sm[i * 64 + d] *= ib;
  __syncthreads();

  float best = -INFINITY; int besti = 0;
  for (int c = 0; c < TSRC; ++c) {
    float s = 0.f;
    #pragma unroll
    for (int d = 0; d < 64; ++d) s += areg[d] * sm[c * 64 + d];
    if (s > best) { best = s; besti = c; }
  }
  if (i == 0) best = -INFINITY;
  __syncthreads();

  sm[i] = best;
  int* smi = (int*)(sm + TSRC);
  smi[i] = besti;
  __syncthreads();

  float ki = sm[i];
  int r = 0;
  for (int j = 0; j < TSRC; ++j) {
    float kj = sm[j];
    if (kj > ki || (kj == ki && j < i)) ++r;
  }
  int* ord = smi + TSRC;
  ord[r] = i;
  __syncthreads();

  order_g[b * TSRC + i] = ord[i];
  if (i < RR) dst_g[b * RR + i] = smi[ord[i]];
}

// ---------------------------------------------------------------------------
// Kernel 4: merge X -> Xm (fp32 residual) + Xm_bf (bf16 GEMM operand).
__global__ __launch_bounds__(256) void merge_kernel(
    const float* __restrict__ X, const int* __restrict__ order,
    const int* __restrict__ dsti, float* __restrict__ Xm,
    u16* __restrict__ Xmb) {
  int row = blockIdx.x;
  int b = row / TM, t2 = row % TM;
  int c = threadIdx.x;
  const float* Xb = X + (size_t)b * TT * DD;
  float out[3];
  if (t2 < UNM) {
    int tok = 2 * order[b * TSRC + RR + t2];
    #pragma unroll
    for (int l = 0; l < 3; ++l) out[l] = Xb[(size_t)tok * DD + c + 256 * l];
  } else {
    int j = t2 - UNM;
    float cnt = 1.f;
    #pragma unroll
    for (int l = 0; l < 3; ++l) out[l] = Xb[(size_t)(2 * j + 1) * DD + c + 256 * l];
    for (int m = 0; m < RR; ++m) {
      if (dsti[b * RR + m] == j) {
        int tok = 2 * order[b * TSRC + m];
        #pragma unroll
        for (int l = 0; l < 3; ++l) out[l] += Xb[(size_t)tok * DD + c + 256 * l];
        cnt += 1.f;
      }
    }
    float inv = 1.f / cnt;
    #pragma unroll
    for (int l = 0; l < 3; ++l) out[l] *= inv;
  }
  #pragma unroll
  for (int l = 0; l < 3; ++l) {
    Xm[(size_t)row * DD + c + 256 * l]  = out[l];
    Xmb[(size_t)row * DD + c + 256 * l] = f2bf(out[l]);
  }
}

// ---------------------------------------------------------------------------
// Kernel 5: MFMA flash attention, barrier-free. bf16 Q/K/ctx + VT (global
// V^T [768][MROW]). Block = (b,h,64-q-tile), 4 waves; wave w owns q-rows
// q0+16w..+15. S^T = K·Q^T (A=K rows, B=Q rows, direct 16B global reads).
// P round-trips through wave-PRIVATE LDS rows (no __syncthreads anywhere).
// PV: A=P (LDS b128, conflict-free groups), B=VT (direct 16B global reads).
// blockIdx: bh = blk%384, qt = blk/384 -> all 8 q-tiles of a (b,h) land on
// the same XCD (384%8==0) so K/VT stay L2-resident.
// NOTE: ctx aliases Q: block reads exactly its own rows (preloaded) and
// writes the same region at the end.
#define NQT 8
__global__ __launch_bounds__(256) void attn_kernel(
    const u16* __restrict__ Q, const u16* __restrict__ K,
    const u16* __restrict__ VT, u16* __restrict__ ctx) {
  __shared__ u16 Pt[64][72];   // P[q-row][token], wave-private rows

  int blk = blockIdx.x;
  int bh = blk % (BNUM * HH);
  int qt = blk / (BNUM * HH);
  int h = bh % HH, b = bh / HH;
  const int t = threadIdx.x;
  const int lane = t & 63, w = t >> 6;
  const int lr = lane & 15, quad = lane >> 4;
  const int q0 = qt * 64;
  const size_t base = (size_t)b * TM * DD + (size_t)h * DHH;

  // Preload Q B-fragments: col n = lr -> q-row q0+16w+lr
  bfrag qf[2];
  {
    const u16* qp = Q + base + (size_t)(q0 + 16 * w + lr) * DD + quad * 8;
    qf[0] = *(const bfrag*)(qp);
    qf[1] = *(const bfrag*)(qp + 32);
  }

  float m_i = -INFINITY, l_i = 0.f;   // state for q-row q0+16w+lr
  ffrag o[4];                          // O[q-rows quad*4+r][dims ni*16+lr]
  #pragma unroll
  for (int ni = 0; ni < 4; ++ni) {
    o[ni].x = 0.f; o[ni].y = 0.f; o[ni].z = 0.f; o[ni].w = 0.f;
  }

  for (int kt = 0; kt < NQT; ++kt) {
    const int k0 = kt * 64;

    // S^T tile: acc[mi] covers tokens k0+mi*16+quad*4+r, q-row lr
    ffrag s4[4];
    #pragma unroll
    for (int mi = 0; mi < 4; ++mi) {
      const u16* kp = K + base + (size_t)(k0 + mi * 16 + lr) * DD + quad * 8;
      bfrag ka0 = *(const bfrag*)(kp);
      bfrag ka1 = *(const bfrag*)(kp + 32);
      ffrag z; z.x = 0.f; z.y = 0.f; z.z = 0.f; z.w = 0.f;
      z = __builtin_amdgcn_mfma_f32_16x16x32_bf16(ka0, qf[0], z, 0, 0, 0);
      s4[mi] = __builtin_amdgcn_mfma_f32_16x16x32_bf16(ka1, qf[1], z, 0, 0, 0);
    }

    // online softmax over lane's 16 scores
    float sc[16];
    float tmax = -INFINITY;
    #pragma unroll
    for (int mi = 0; mi < 4; ++mi)
      #pragma unroll
      for (int r = 0; r < 4; ++r) {
        int tok = k0 + mi * 16 + quad * 4 + r;
        float v = (tok < TM) ? s4[mi][r] * 0.125f : -INFINITY;
        sc[mi * 4 + r] = v;
        tmax = fmaxf(tmax, v);
      }
    tmax = fmaxf(tmax, __shfl_xor(tmax, 16));
    tmax = fmaxf(tmax, __shfl_xor(tmax, 32));
    float nm = fmaxf(m_i, tmax);
    float alpha = __expf(m_i - nm);    // first tile: exp(-inf)=0
    float psum = 0.f;
    u16 pb[16];
    #pragma unroll
    for (int i = 0; i < 16; ++i) {
      float p = __expf(sc[i] - nm);
      psum += p;
      pb[i] = f2bf(p);
    }
    psum += __shfl_xor(psum, 16);
    psum += __shfl_xor(psum, 32);
    l_i = l_i * alpha + psum;
    m_i = nm;

    // write P (wave-private rows): row 16w+lr, cols mi*16+quad*4..+3
    #pragma unroll
    for (int mi = 0; mi < 4; ++mi) {
      u32 lo = (u32)pb[mi * 4 + 0] | ((u32)pb[mi * 4 + 1] << 16);
      u32 hi = (u32)pb[mi * 4 + 2] | ((u32)pb[mi * 4 + 3] << 16);
      u32* dst = (u32*)&Pt[16 * w + lr][mi * 16 + quad * 4];
      dst[0] = lo; dst[1] = hi;
    }

    // rescale O (row = quad*4+r -> alpha from lane r of this 16-group)
    float al[4];
    #pragma unroll
    for (int r = 0; r < 4; ++r) al[r] = __shfl(alpha, quad * 4 + r);
    #pragma unroll
    for (int ni = 0; ni < 4; ++ni)
      #pragma unroll
      for (int r = 0; r < 4; ++r) o[ni][r] *= al[r];

    // PV: A = P row (LDS), B = VT rows (global, contiguous tokens)
    bfrag pa0 = *(const bfrag*)&Pt[16 * w + lr][quad * 8];
    bfrag pa1 = *(const bfrag*)&Pt[16 * w + lr][32 + quad * 8];
    #pragma unroll
    for (int ni = 0; ni < 4; ++ni) {
      const u16* vp = VT + (size_t)(h * DHH + ni * 16 + lr) * MROW
                         + (size_t)b * TM + k0 + quad * 8;
      bfrag vb0 = *(const bfrag*)(vp);
      bfrag vb1 = *(const bfrag*)(vp + 32);
      o[ni] = __builtin_amdgcn_mfma_f32_16x16x32_bf16(pa0, vb0, o[ni], 0, 0, 0);
      o[ni] = __builtin_amdgcn_mfma_f32_16x16x32_bf16(pa1, vb1, o[ni], 0, 0, 0);
    }
  }

  // epilogue: O /= l, store bf16
  float invl[4];
  #pragma unroll
  for (int r = 0; r < 4; ++r) {
    float lv = __shfl(l_i, quad * 4 + r);
    invl[r] = 1.f / lv;
  }
  #pragma unroll
  for (int r = 0; r < 4; ++r) {
    int row = q0 + 16 * w + quad * 4 + r;
    if (row < TM) {
      size_t g = base + (size_t)row * DD + lr;
      #pragma unroll
      for (int ni = 0; ni < 4; ++ni)
        ctx[g + ni * 16] = f2bf(o[ni][r] * invl[r]);
    }
  }
}

// ---------------------------------------------------------------------------
// Kernel 7: in-place LayerNorm on d_out rows (768 wide).
__global__ __launch_bounds__(256) void ln_kernel(
    float* __restrict__ Y, const float* __restrict__ g,
    const float* __restrict__ beta) {
  __shared__ float red[4];
  int row = blockIdx.x, t = threadIdx.x;
  size_t baseo = (size_t)row * DD;
  float x[3];
  #pragma unroll
  for (int l = 0; l < 3; ++l) x[l] = Y[baseo + t + 256 * l];
  float s = x[0] + x[1] + x[2];
  #pragma unroll
  for (int off = 32; off > 0; off >>= 1) s += __shfl_down(s, off, 64);
  if ((t & 63) == 0) red[t >> 6] = s;
  __syncthreads();
  float mu = (red[0] + red[1] + red[2] + red[3]) * (1.f / 768.f);
  __syncthreads();
  float d0 = x[0] - mu, d1 = x[1] - mu, d2 = x[2] - mu;
  float sq = d0 * d0 + d1 * d1 + d2 * d2;
  #pragma unroll
  for (int off = 32; off > 0; off >>= 1) sq += __shfl_down(sq, off, 64);
  if ((t & 63) == 0) red[t >> 6] = sq;
  __syncthreads();
  float var = (red[0] + red[1] + red[2] + red[3]) * (1.f / 768.f);
  float inv = rsqrtf(var + 1e-12f);
  #pragma unroll
  for (int l = 0; l < 3; ++l) {
    int c = t + 256 * l;
    Y[baseo + c] = (x[l] - mu) * inv * g[c] + beta[c];
  }
}

// ---------------------------------------------------------------------------
extern "C" void kernel_launch(void* const* d_in, const int* in_sizes, int n_in,
                              void* d_out, int out_size, void* d_ws, size_t ws_size,
                              hipStream_t stream) {
  const float* X    = (const float*)d_in[0];
  const float* Wq   = (const float*)d_in[1];
  const float* bq   = (const float*)d_in[2];
  const float* Wk   = (const float*)d_in[3];
  const float* bk   = (const float*)d_in[4];
  const float* Wv   = (const float*)d_in[5];
  const float* bv   = (const float*)d_in[6];
  const float* Wo   = (const float*)d_in[7];
  const float* bo   = (const float*)d_in[8];
  const float* ln_g = (const float*)d_in[9];
  const float* ln_b = (const float*)d_in[10];
  float* out = (float*)d_out;

  const size_t metric_n = (size_t)16384 * 64;
  const size_t wkr_n    = (size_t)768 * 64 + 64;
  const size_t idx_n    = (size_t)BNUM * TSRC + BNUM * RR;
  const size_t buf_n    = (size_t)MROW * DD;
  const size_t w_n      = (size_t)DD * DD;
  const size_t f32_elems = metric_n + wkr_n + idx_n + buf_n;
  const size_t u16_elems = 4 * buf_n + 4 * w_n;
  const size_t needed = f32_elems * 4 + u16_elems * 2;
  if (ws_size < needed) return;

  float* ws = (float*)d_ws;
  float* metric  = ws;
  float* Wkr     = metric + metric_n;
  float* bkr     = Wkr + (size_t)768 * 64;
  int*   order_g = (int*)(bkr + 64);
  int*   dst_g   = order_g + BNUM * TSRC;
  float* Xm      = (float*)(dst_g + BNUM * RR);
  u16*   Xmb     = (u16*)(Xm + buf_n);
  u16*   Qmb     = Xmb + buf_n;
  u16*   Kmb     = Qmb + buf_n;
  u16*   VTb     = Kmb + buf_n;     // V^T: [768][MROW]
  u16*   WqT     = VTb + buf_n;
  u16*   WkT     = WqT + w_n;
  u16*   WvT     = WkT + w_n;
  u16*   WoT     = WvT + w_n;
  u16*   ctxb    = Qmb;   // alias: safe, see attn_kernel note

  wkr_kernel<<<(768 * 64) / 256, 256, 0, stream>>>(Wk, bk, Wkr, bkr);
  wconv_kernel<<<dim3(12, 12, 4), 256, 0, stream>>>(
      Wq, Wk, Wv, Wo, WqT, WkT, WvT, WoT);
  gemm_f32_kernel<<<dim3(16384 / 32, 1), 256, 0, stream>>>(
      X, Wkr, bkr, metric, 16384, 64, 768);
  tome_kernel<<<BNUM, 256, 0, stream>>>(metric, order_g, dst_g);
  merge_kernel<<<MROW, 256, 0, stream>>>(X, order_g, dst_g, Xm, Xmb);
  // Q, K: [MROW][768]
  mfma_gemm_kernel<true, false, false><<<dim3(MROW / 128, DD / 128), 256, 0, stream>>>(
      Xmb, WqT, bq, nullptr, nullptr, Qmb, MROW, DD, DD);
  mfma_gemm_kernel<true, false, false><<<dim3(MROW / 128, DD / 128), 256, 0, stream>>>(
      Xmb, WkT, bk, nullptr, nullptr, Kmb, MROW, DD, DD);
  // V^T directly: VT[768][MROW] = WvT(768x768) x Xmb^T, bias per ROW
  mfma_gemm_kernel<true, false, true><<<dim3(DD / 128, MROW / 128), 256, 0, stream>>>(
      WvT, Xmb, bv, nullptr, nullptr, VTb, DD, MROW, DD);
  attn_kernel<<<BNUM * HH * NQT, 256, 0, stream>>>(Qmb, Kmb, VTb, ctxb);
  mfma_gemm_kernel<false, true, false><<<dim3(MROW / 128, DD / 128), 256, 0, stream>>>(
      ctxb, WoT, bo, Xm, out, nullptr, MROW, DD, DD);
  ln_kernel<<<MROW, 256, 0, stream>>>(out, ln_g, ln_b);
}